// Round 11
// baseline (115.506 us; speedup 1.0000x reference)
//
#include <hip/hip_runtime.h>
#include <math.h>

#define NN 64
#define DD 128
#define HH 256
#define FLAG_MAGIC 0x5CA1AB1E

typedef __attribute__((ext_vector_type(8))) short short8;
typedef __attribute__((ext_vector_type(4))) float f32x4;

// ws layout (floats):
//   P    [64][256] @ 0        (x @ cdW1[0:128]   + cdb1)
//   Q    [64][256] @ 16384    (x @ cdW1[128:256])
//   A    [64][256] @ 32768    (x @ cfW1[0:128]   + cfb1)
//   B    [64][256] @ 49152    (x @ cfW1[128:256])
//   C4   [64 d4][64 k]float4 @ 65536  (x @ cfW1[256:384], transposed)
//   W2T  bf16 [128 c][256 t] @ 81920  (cdW2 transposed, bf16)  (64 KB)
//   flags int[512]            @ 98304 (magic-valued barrier; poison-safe,
//                                      replay-safe: staging rewrites identical bits)

__device__ __forceinline__ short f2bf(float f) {
    unsigned u = __float_as_uint(f);
    unsigned r = (u + 0x7fffu + ((u >> 16) & 1u)) >> 16;
    return (short)r;
}

// ONE kernel, grid 512 x 256thr, >=2 blocks/CU guaranteed -> all resident -> SW
// barrier is deadlock-free (1024-block capacity >= 512).
// Phase 1 (staging units, blocks 0..202 — R6-validated code):
//   0..191 : projections, grp=bid>>6 (0: P,Q | 1: A,B | 2: C4), node n=bid&63
//   192..199: W2T bf16 transpose (16 c's each)
//   200    : intervention MLP      201..202: out3 row copies
// Barrier: flags[bid]=MAGIC (release/agent); spin-acquire on flags[0..202].
// Phase 2: bids 0..255 pairs MFMA unit; bids 256..511 zero-LDS triple unit.
__global__ __launch_bounds__(256, 2) void k_one(
    const float* __restrict__ x, const int* __restrict__ inode,
    const float* __restrict__ ival,
    const float* __restrict__ cdW1, const float* __restrict__ cdb1,
    const float* __restrict__ cdW2, const float* __restrict__ cdb2,
    const float* __restrict__ cdW3, const float* __restrict__ cdb3,
    const float* __restrict__ cfW1, const float* __restrict__ cfb1,
    const float* __restrict__ cfW2, const float* __restrict__ cfb2,
    const float* __restrict__ ipW1, const float* __restrict__ ipb1,
    const float* __restrict__ ipW2, const float* __restrict__ ipb2,
    float* __restrict__ ws, float* __restrict__ causal,
    float* __restrict__ conf, float* __restrict__ out3)
{
    __shared__ float smem[1536];   // 6 KB: projection 1152, intervention 1536, pairs 64
    const int bid = blockIdx.x;
    const int tid = threadIdx.x;

    // ================= PHASE 1: staging (blocks 0..202) =================
    if (bid < 192) {
        // projections for node n: grp 0 -> P,Q; grp 1 -> A,B; grp 2 -> C4
        const int n   = bid & 63;
        const int grp = bid >> 6;
        float*  xs  = smem;                     // 128
        float4* red = (float4*)(smem + 128);    // [4][64]
        if (tid < DD) xs[tid] = x[n * DD + tid];
        __syncthreads();
        const int c4 = tid & 63;
        const int dg = tid >> 6;                // 0..3, 32 d's each
        const int nproj = (grp == 2) ? 1 : 2;
        for (int it = 0; it < nproj; ++it) {
            const float* Wp = (grp == 0) ? (it == 0 ? cdW1 : cdW1 + DD * HH)
                            : (grp == 1) ? (it == 0 ? cfW1 : cfW1 + DD * HH)
                                         : (cfW1 + 2 * DD * HH);
            const float4* Wp4 = (const float4*)Wp;
            float4 acc = {0.f, 0.f, 0.f, 0.f};
#pragma unroll
            for (int round = 0; round < 2; ++round) {
                float4 w[16];
#pragma unroll
                for (int q = 0; q < 16; ++q)
                    w[q] = Wp4[(dg * 32 + round * 16 + q) * 64 + c4];
#pragma unroll
                for (int q = 0; q < 16; ++q) {
                    const float xv = xs[dg * 32 + round * 16 + q];
                    acc.x += xv * w[q].x; acc.y += xv * w[q].y;
                    acc.z += xv * w[q].z; acc.w += xv * w[q].w;
                }
            }
            red[dg * 64 + c4] = acc;
            __syncthreads();
            if (tid < 64) {
                const float4 r0 = red[tid],       r1 = red[64 + tid];
                const float4 r2 = red[128 + tid], r3 = red[192 + tid];
                float4 s;
                s.x = r0.x + r1.x + r2.x + r3.x;
                s.y = r0.y + r1.y + r2.y + r3.y;
                s.z = r0.z + r1.z + r2.z + r3.z;
                s.w = r0.w + r1.w + r2.w + r3.w;
                if (grp == 0) {
                    if (it == 0) {
                        const float4 b = ((const float4*)cdb1)[tid];
                        s.x += b.x; s.y += b.y; s.z += b.z; s.w += b.w;
                        ((float4*)(ws))[n * 64 + tid] = s;
                    } else {
                        ((float4*)(ws + 16384))[n * 64 + tid] = s;
                    }
                } else if (grp == 1) {
                    if (it == 0) {
                        const float4 b = ((const float4*)cfb1)[tid];
                        s.x += b.x; s.y += b.y; s.z += b.z; s.w += b.w;
                        ((float4*)(ws + 32768))[n * 64 + tid] = s;
                    } else {
                        ((float4*)(ws + 49152))[n * 64 + tid] = s;
                    }
                } else {
                    ((float4*)(ws + 65536))[tid * 64 + n] = s;  // C4[d4][n]
                }
            }
            if (it + 1 < nproj) __syncthreads();
        }
    } else if (bid < 200) {
        // W2T[c][t] = bf16(cdW2[t][c]); 16 c's per block
        unsigned short* W2T = (unsigned short*)(ws + 81920);
        const int c  = (bid - 192) * 16 + (tid >> 4);
        const int t0 = (tid & 15) * 16;
        float v[16];
#pragma unroll
        for (int e = 0; e < 16; ++e) v[e] = cdW2[(t0 + e) * 128 + c];
        unsigned short pk[16];
#pragma unroll
        for (int e = 0; e < 16; ++e) pk[e] = (unsigned short)f2bf(v[e]);
        *(ulong2*)(W2T + c * HH + t0)     = ((ulong2*)pk)[0];
        *(ulong2*)(W2T + c * HH + t0 + 8) = ((ulong2*)pk)[1];
    } else if (bid == 200) {
        // intervention MLP: [x[node], v](129) -> relu 256 -> 128
        float*  in_s = smem;                    // 132
        float*  h_s  = smem + 132;              // 256
        float4* red  = (float4*)(smem + 512);   // 256 float4
        const int node = inode[0];
        if (tid < DD) in_s[tid] = x[node * DD + tid];
        if (tid == DD) in_s[DD] = ival[0];
        __syncthreads();
        {
            const int c4 = tid & 63;
            const int dg = tid >> 6;
            const float4* W1v = (const float4*)ipW1;
            float4 acc = {0.f, 0.f, 0.f, 0.f};
#pragma unroll 8
            for (int r = 0; r < 32; ++r) {
                const int d = dg * 32 + r;
                const float xv = in_s[d];
                const float4 w = W1v[d * 64 + c4];
                acc.x += xv * w.x; acc.y += xv * w.y;
                acc.z += xv * w.z; acc.w += xv * w.w;
            }
            if (dg == 0) {
                const float xv = in_s[128];
                const float4 w = W1v[128 * 64 + c4];
                acc.x += xv * w.x; acc.y += xv * w.y;
                acc.z += xv * w.z; acc.w += xv * w.w;
            }
            red[dg * 64 + c4] = acc;
        }
        __syncthreads();
        if (tid < 64) {
            const float4 r0 = red[tid],       r1 = red[64 + tid];
            const float4 r2 = red[128 + tid], r3 = red[192 + tid];
            const float4 b = ((const float4*)ipb1)[tid];
            float4 h;
            h.x = fmaxf(r0.x + r1.x + r2.x + r3.x + b.x, 0.f);
            h.y = fmaxf(r0.y + r1.y + r2.y + r3.y + b.y, 0.f);
            h.z = fmaxf(r0.z + r1.z + r2.z + r3.z + b.z, 0.f);
            h.w = fmaxf(r0.w + r1.w + r2.w + r3.w + b.w, 0.f);
            ((float4*)h_s)[tid] = h;
        }
        __syncthreads();
        {
            const int c4 = tid & 31;
            const int ug = tid >> 5;
            const float4* W2v = (const float4*)ipW2;
            float4 acc = {0.f, 0.f, 0.f, 0.f};
#pragma unroll 8
            for (int r = 0; r < 32; ++r) {
                const int uu = ug * 32 + r;
                const float hv = h_s[uu];
                const float4 w = W2v[uu * 32 + c4];
                acc.x += hv * w.x; acc.y += hv * w.y;
                acc.z += hv * w.z; acc.w += hv * w.w;
            }
            red[ug * 32 + c4] = acc;
        }
        __syncthreads();
        if (tid < 32) {
            float4 s = ((const float4*)ipb2)[tid];
#pragma unroll
            for (int g = 0; g < 8; ++g) {
                const float4 r = red[g * 32 + tid];
                s.x += r.x; s.y += r.y; s.z += r.z; s.w += r.w;
            }
            ((float4*)(out3 + node * DD))[tid] = s;
        }
    } else if (bid < 203) {
        // out3 copies (rows != node), 32 rows per block
        const int node = inode[0];
        const int n = (bid - 201) * 32 + (tid >> 3);
        const int part = tid & 7;
        if (n != node) {
            const float4* src = (const float4*)(x + n * DD);
            float4* dst = (float4*)(out3 + n * DD);
#pragma unroll
            for (int e = 0; e < 4; ++e) dst[part * 4 + e] = src[part * 4 + e];
        }
    }

    // ================= GRID BARRIER (magic flags, wait on 0..202) ============
    {
        int* flags = (int*)(ws + 98304);
        __syncthreads();
        __threadfence();   // release phase-1 ws/out3 writes to device scope
        if (tid == 0)
            __hip_atomic_store(&flags[bid], FLAG_MAGIC,
                               __ATOMIC_RELEASE, __HIP_MEMORY_SCOPE_AGENT);
        if (tid < 203) {
            while (__hip_atomic_load(&flags[tid], __ATOMIC_ACQUIRE,
                                     __HIP_MEMORY_SCOPE_AGENT) != FLAG_MAGIC) {
                __builtin_amdgcn_s_sleep(1);
            }
        }
        __syncthreads();
        __threadfence();   // acquire: no stale cache lines for ws reads
    }

    // ================= PHASE 2 =================
    if (bid < 256) {
        // ---- causal pairs via bf16 MFMA (unit = bid)
        const int i  = bid >> 2;
        const int j0 = (bid & 3) * 16;
        const int wid  = tid >> 6;
        const int lane = tid & 63;
        const int lo = lane & 15;
        const int hi = lane >> 4;
        const int n0 = wid * 32;

        const float* Prow = ws + i * HH;
        const float* Qrow = ws + 16384 + (j0 + lo) * HH;
        const unsigned short* W2T = (const unsigned short*)(ws + 81920);

        f32x4 acc0 = {0.f, 0.f, 0.f, 0.f};
        f32x4 acc1 = {0.f, 0.f, 0.f, 0.f};
#pragma unroll
        for (int step = 0; step < 8; ++step) {
            const int kb = step * 32 + hi * 8;
            const float4 pa = *(const float4*)(Prow + kb);
            const float4 pb = *(const float4*)(Prow + kb + 4);
            const float4 qa = *(const float4*)(Qrow + kb);
            const float4 qb = *(const float4*)(Qrow + kb + 4);
            short8 af;
            af[0] = f2bf(fmaxf(pa.x + qa.x, 0.f));
            af[1] = f2bf(fmaxf(pa.y + qa.y, 0.f));
            af[2] = f2bf(fmaxf(pa.z + qa.z, 0.f));
            af[3] = f2bf(fmaxf(pa.w + qa.w, 0.f));
            af[4] = f2bf(fmaxf(pb.x + qb.x, 0.f));
            af[5] = f2bf(fmaxf(pb.y + qb.y, 0.f));
            af[6] = f2bf(fmaxf(pb.z + qb.z, 0.f));
            af[7] = f2bf(fmaxf(pb.w + qb.w, 0.f));
            const short8 b0 = *(const short8*)(W2T + (n0 + lo) * HH + kb);
            const short8 b1 = *(const short8*)(W2T + (n0 + 16 + lo) * HH + kb);
            acc0 = __builtin_amdgcn_mfma_f32_16x16x32_bf16(af, b0, acc0, 0, 0, 0);
            acc1 = __builtin_amdgcn_mfma_f32_16x16x32_bf16(af, b1, acc1, 0, 0, 0);
        }
        const int c0 = n0 + lo;
        const int c1 = n0 + 16 + lo;
        const float b2a = cdb2[c0], b2b = cdb2[c1];
        const float w3a = cdW3[c0], w3b = cdW3[c1];
        float pr[4];
#pragma unroll
        for (int r = 0; r < 4; ++r) {
            pr[r] = fmaxf(acc0[r] + b2a, 0.f) * w3a
                  + fmaxf(acc1[r] + b2b, 0.f) * w3b;
        }
#pragma unroll
        for (int m = 1; m <= 8; m <<= 1) {
#pragma unroll
            for (int r = 0; r < 4; ++r) pr[r] += __shfl_xor(pr[r], m, 64);
        }
        float* zp = smem;   // [4][16], safe: all phase-1 smem use ended pre-barrier
        if (lo == 0) {
#pragma unroll
            for (int r = 0; r < 4; ++r) zp[wid * 16 + hi * 4 + r] = pr[r];
        }
        __syncthreads();
        if (tid < 16) {
            const float z = zp[tid] + zp[16 + tid] + zp[32 + tid] + zp[48 + tid]
                          + cdb3[0];
            const float sg = 1.f / (1.f + expf(-z));
            const int j = j0 + tid;
            causal[i * NN + j] = (i == j) ? 0.f : sg;
        }
    } else {
        // ---- confounder triples, zero-LDS (unit = bid-256), 4-wide chunks
        const int u = bid - 256;
        const float* A  = ws + 32768;
        const float* B  = ws + 49152;
        const float* C4 = ws + 65536;
        const int i  = u >> 2;
        const int j0 = (u & 3) * 16;
        const int k   = tid & 63;
        const int jj2 = tid >> 6;
        const float4* C4v = (const float4*)C4;
        const float4* Av  = (const float4*)(A + i * HH);
        const float4* wv  = (const float4*)cfW2;
        float acc[4] = {0.f, 0.f, 0.f, 0.f};
        for (int ch = 0; ch < 16; ++ch) {
            float4 cr[4], av[4], wr[4];
#pragma unroll
            for (int q = 0; q < 4; ++q) {
                cr[q] = C4v[(ch * 4 + q) * 64 + k];   // coalesced over k-lanes
                av[q] = Av[ch * 4 + q];               // wave-uniform broadcast
                wr[q] = wv[ch * 4 + q];               // wave-uniform broadcast
            }
#pragma unroll
            for (int p = 0; p < 4; ++p) {
                const int j = j0 + p * 4 + jj2;
                const float4* Bv = (const float4*)(B + j * HH);
                float4 bv[4];
#pragma unroll
                for (int q = 0; q < 4; ++q) bv[q] = Bv[ch * 4 + q];
                float a = acc[p];
#pragma unroll
                for (int q = 0; q < 4; ++q) {
                    const float sx = av[q].x + bv[q].x;
                    const float sy = av[q].y + bv[q].y;
                    const float sz = av[q].z + bv[q].z;
                    const float sw = av[q].w + bv[q].w;
                    a += fmaxf(sx + cr[q].x, 0.f) * wr[q].x;
                    a += fmaxf(sy + cr[q].y, 0.f) * wr[q].y;
                    a += fmaxf(sz + cr[q].z, 0.f) * wr[q].z;
                    a += fmaxf(sw + cr[q].w, 0.f) * wr[q].w;
                }
                acc[p] = a;
            }
        }
        const float b2 = cfb2[0];
#pragma unroll
        for (int p = 0; p < 4; ++p) {
            const int j = j0 + p * 4 + jj2;
            const float z = acc[p] + b2;
            const float sg = 1.f / (1.f + expf(-z));
            const bool distinct = (i != j) && (j != k) && (i != k);
            conf[(i * NN + j) * NN + k] = distinct ? sg : 0.f;
        }
    }
}

extern "C" void kernel_launch(void* const* d_in, const int* in_sizes, int n_in,
                              void* d_out, int out_size, void* d_ws, size_t ws_size,
                              hipStream_t stream) {
    const float* x    = (const float*)d_in[0];
    const int*   node = (const int*)d_in[1];
    const float* ival = (const float*)d_in[2];
    const float* cdW1 = (const float*)d_in[3];
    const float* cdb1 = (const float*)d_in[4];
    const float* cdW2 = (const float*)d_in[5];
    const float* cdb2 = (const float*)d_in[6];
    const float* cdW3 = (const float*)d_in[7];
    const float* cdb3 = (const float*)d_in[8];
    const float* cfW1 = (const float*)d_in[9];
    const float* cfb1 = (const float*)d_in[10];
    const float* cfW2 = (const float*)d_in[11];
    const float* cfb2 = (const float*)d_in[12];
    const float* ipW1 = (const float*)d_in[13];
    const float* ipb1 = (const float*)d_in[14];
    const float* ipW2 = (const float*)d_in[15];
    const float* ipb2 = (const float*)d_in[16];

    float* out    = (float*)d_out;
    float* causal = out;                           // 4096
    float* conf   = out + NN * NN;                 // 262144
    float* out3   = out + NN * NN + NN * NN * NN;  // 8192
    float* wsf    = (float*)d_ws;

    k_one<<<dim3(512), dim3(256), 0, stream>>>(
        x, node, ival, cdW1, cdb1, cdW2, cdb2, cdW3, cdb3,
        cfW1, cfb1, cfW2, cfb2, ipW1, ipb1, ipW2, ipb2,
        wsf, causal, conf, out3);
}

// Round 12
// 38.644 us; speedup vs baseline: 2.9889x; 2.9889x over previous
//
#include <hip/hip_runtime.h>
#include <math.h>

#define NN 64
#define DD 128
#define HH 256

typedef __attribute__((ext_vector_type(8))) short short8;
typedef __attribute__((ext_vector_type(4))) float f32x4;

// ws layout (floats):
//   P    [64][256] @ 0        (x @ cdW1[0:128]   + cdb1)
//   Q    [64][256] @ 16384    (x @ cdW1[128:256])
//   A    [64][256] @ 32768    (x @ cfW1[0:128]   + cfb1)
//   B    [64][256] @ 49152    (x @ cfW1[128:256])
//   C4   [64 d4][64 k]float4 @ 65536  (x @ cfW1[256:384], transposed)
//   W2T  bf16 [128 c][256 t] @ 81920  (cdW2 transposed, bf16)  (64 KB)

__device__ __forceinline__ short f2bf(float f) {
    unsigned u = __float_as_uint(f);
    unsigned r = (u + 0x7fffu + ((u >> 16) & 1u)) >> 16;
    return (short)r;
}

// MEASUREMENT probe: truly empty kernel. 5 copies appended after k_main;
// per-node graph overhead L = (dur - 31.3)/5. Does not touch any buffer.
__global__ void k_empty() {}

// Kernel A, 512 thr, grid 328. Blocks 0..319: projection p=bid>>6, node n=bid&63.
// Blocks 320..327: cdW2 -> W2T bf16 transpose, one latency round.
__global__ __launch_bounds__(512) void k_stage(
    const float* __restrict__ x, const int* __restrict__ inode,
    const float* __restrict__ cdW1, const float* __restrict__ cdb1,
    const float* __restrict__ cdW2,
    const float* __restrict__ cfW1, const float* __restrict__ cfb1,
    float* __restrict__ ws, float* __restrict__ out3)
{
    const int bid = blockIdx.x;
    const int tid = threadIdx.x;
    if (bid < 320) {
        __shared__ float xs[DD];
        __shared__ float4 red[8][64];
        const int p = bid >> 6;
        const int n = bid & 63;
        if (tid < DD) xs[tid] = x[n * DD + tid];
        __syncthreads();
        const int c4 = tid & 63;   // float4 column group
        const int dg = tid >> 6;   // 0..7, 16 d's each
        const float* Wp = (p == 0) ? cdW1
                        : (p == 1) ? (cdW1 + DD * HH)
                                   : (cfW1 + (p - 2) * DD * HH);
        const float4* Wp4 = (const float4*)Wp;
        float4 w[16];
#pragma unroll
        for (int q = 0; q < 16; ++q) w[q] = Wp4[(dg * 16 + q) * 64 + c4];
        float4 acc = {0.f, 0.f, 0.f, 0.f};
#pragma unroll
        for (int q = 0; q < 16; ++q) {
            const float xv = xs[dg * 16 + q];
            acc.x += xv * w[q].x; acc.y += xv * w[q].y;
            acc.z += xv * w[q].z; acc.w += xv * w[q].w;
        }
        red[dg][c4] = acc;
        __syncthreads();
        if (tid < 64) {
            float4 s = {0.f, 0.f, 0.f, 0.f};
#pragma unroll
            for (int g = 0; g < 8; ++g) {
                const float4 r = red[g][tid];
                s.x += r.x; s.y += r.y; s.z += r.z; s.w += r.w;
            }
            if (p == 0) {
                const float4 b = ((const float4*)cdb1)[tid];
                s.x += b.x; s.y += b.y; s.z += b.z; s.w += b.w;
                ((float4*)(ws))[n * 64 + tid] = s;
            } else if (p == 1) {
                ((float4*)(ws + 16384))[n * 64 + tid] = s;
            } else if (p == 2) {
                const float4 b = ((const float4*)cfb1)[tid];
                s.x += b.x; s.y += b.y; s.z += b.z; s.w += b.w;
                ((float4*)(ws + 32768))[n * 64 + tid] = s;
            } else if (p == 3) {
                ((float4*)(ws + 49152))[n * 64 + tid] = s;
            } else {
                ((float4*)(ws + 65536))[tid * 64 + n] = s;  // C4[d4][n]
            }
        }
    } else {
        // W2T[c][t] = bf16(cdW2[t][c]); 16 c's per block, 32 threads per c
        unsigned short* W2T = (unsigned short*)(ws + 81920);
        const int c  = (bid - 320) * 16 + (tid >> 5);
        const int t0 = (tid & 31) * 8;
        float v[8];
#pragma unroll
        for (int e = 0; e < 8; ++e) v[e] = cdW2[(t0 + e) * 128 + c];
        unsigned short pk[8];
#pragma unroll
        for (int e = 0; e < 8; ++e) pk[e] = (unsigned short)f2bf(v[e]);
        *(ulong2*)(W2T + c * HH + t0) = *(ulong2*)pk;
    }
}

// Kernel B, 256 thr, grid 515.
__global__ __launch_bounds__(256) void k_main(
    const float* __restrict__ ws, const float* __restrict__ x,
    const int* __restrict__ inode, const float* __restrict__ ival,
    const float* __restrict__ cdb2, const float* __restrict__ cdW3,
    const float* __restrict__ cdb3,
    const float* __restrict__ cfW2, const float* __restrict__ cfb2,
    const float* __restrict__ ipW1, const float* __restrict__ ipb1,
    const float* __restrict__ ipW2, const float* __restrict__ ipb2,
    float* __restrict__ causal, float* __restrict__ conf,
    float* __restrict__ out3)
{
    const int bid = blockIdx.x;
    const int tid = threadIdx.x;
    if (bid < 256) {
        // ---- causal pairs via bf16 MFMA, no LDS main loop
        const int i  = bid >> 2;
        const int j0 = (bid & 3) * 16;
        const int wid  = tid >> 6;
        const int lane = tid & 63;
        const int lo = lane & 15;
        const int hi = lane >> 4;
        const int n0 = wid * 32;

        const float* Prow = ws + i * HH;
        const float* Qrow = ws + 16384 + (j0 + lo) * HH;
        const unsigned short* W2T = (const unsigned short*)(ws + 81920);

        f32x4 acc0 = {0.f, 0.f, 0.f, 0.f};
        f32x4 acc1 = {0.f, 0.f, 0.f, 0.f};
#pragma unroll
        for (int step = 0; step < 8; ++step) {
            const int kb = step * 32 + hi * 8;
            const float4 pa = *(const float4*)(Prow + kb);
            const float4 pb = *(const float4*)(Prow + kb + 4);
            const float4 qa = *(const float4*)(Qrow + kb);
            const float4 qb = *(const float4*)(Qrow + kb + 4);
            short8 af;
            af[0] = f2bf(fmaxf(pa.x + qa.x, 0.f));
            af[1] = f2bf(fmaxf(pa.y + qa.y, 0.f));
            af[2] = f2bf(fmaxf(pa.z + qa.z, 0.f));
            af[3] = f2bf(fmaxf(pa.w + qa.w, 0.f));
            af[4] = f2bf(fmaxf(pb.x + qb.x, 0.f));
            af[5] = f2bf(fmaxf(pb.y + qb.y, 0.f));
            af[6] = f2bf(fmaxf(pb.z + qb.z, 0.f));
            af[7] = f2bf(fmaxf(pb.w + qb.w, 0.f));
            const short8 b0 = *(const short8*)(W2T + (n0 + lo) * HH + kb);
            const short8 b1 = *(const short8*)(W2T + (n0 + 16 + lo) * HH + kb);
            acc0 = __builtin_amdgcn_mfma_f32_16x16x32_bf16(af, b0, acc0, 0, 0, 0);
            acc1 = __builtin_amdgcn_mfma_f32_16x16x32_bf16(af, b1, acc1, 0, 0, 0);
        }
        const int c0 = n0 + lo;
        const int c1 = n0 + 16 + lo;
        const float b2a = cdb2[c0], b2b = cdb2[c1];
        const float w3a = cdW3[c0], w3b = cdW3[c1];
        float pr[4];
#pragma unroll
        for (int r = 0; r < 4; ++r) {
            pr[r] = fmaxf(acc0[r] + b2a, 0.f) * w3a
                  + fmaxf(acc1[r] + b2b, 0.f) * w3b;
        }
#pragma unroll
        for (int m = 1; m <= 8; m <<= 1) {
#pragma unroll
            for (int r = 0; r < 4; ++r) pr[r] += __shfl_xor(pr[r], m, 64);
        }
        __shared__ float zp[4][16];
        if (lo == 0) {
#pragma unroll
            for (int r = 0; r < 4; ++r) zp[wid][hi * 4 + r] = pr[r];
        }
        __syncthreads();
        if (tid < 16) {
            const float z = zp[0][tid] + zp[1][tid] + zp[2][tid] + zp[3][tid] + cdb3[0];
            const float sg = 1.f / (1.f + expf(-z));
            const int j = j0 + tid;
            causal[i * NN + j] = (i == j) ? 0.f : sg;
        }
    } else if (bid < 512) {
        // ---- confounder triples, zero-LDS
        const int u = bid - 256;
        const float* A  = ws + 32768;
        const float* B  = ws + 49152;
        const float* C4 = ws + 65536;
        const int i  = u >> 2;
        const int j0 = (u & 3) * 16;
        const int k   = tid & 63;
        const int jj2 = tid >> 6;
        const float4* C4v = (const float4*)C4;
        const float4* Av  = (const float4*)(A + i * HH);
        const float4* wv  = (const float4*)cfW2;
        float acc[4] = {0.f, 0.f, 0.f, 0.f};
        for (int ch = 0; ch < 8; ++ch) {
            float4 cr[8], av[8], wr[8];
#pragma unroll
            for (int q = 0; q < 8; ++q) {
                cr[q] = C4v[(ch * 8 + q) * 64 + k];   // coalesced over k-lanes
                av[q] = Av[ch * 8 + q];               // wave-uniform broadcast (L1)
                wr[q] = wv[ch * 8 + q];               // wave-uniform broadcast (L1)
            }
#pragma unroll
            for (int p = 0; p < 4; ++p) {
                const int j = j0 + p * 4 + jj2;
                const float4* Bv = (const float4*)(B + j * HH);
                float4 bv[8];
#pragma unroll
                for (int q = 0; q < 8; ++q) bv[q] = Bv[ch * 8 + q];  // broadcast
                float a = acc[p];
#pragma unroll
                for (int q = 0; q < 8; ++q) {
                    const float sx = av[q].x + bv[q].x;
                    const float sy = av[q].y + bv[q].y;
                    const float sz = av[q].z + bv[q].z;
                    const float sw = av[q].w + bv[q].w;
                    a += fmaxf(sx + cr[q].x, 0.f) * wr[q].x;
                    a += fmaxf(sy + cr[q].y, 0.f) * wr[q].y;
                    a += fmaxf(sz + cr[q].z, 0.f) * wr[q].z;
                    a += fmaxf(sw + cr[q].w, 0.f) * wr[q].w;
                }
                acc[p] = a;
            }
        }
        const float b2 = cfb2[0];
#pragma unroll
        for (int p = 0; p < 4; ++p) {
            const int j = j0 + p * 4 + jj2;
            const float z = acc[p] + b2;
            const float sg = 1.f / (1.f + expf(-z));
            const bool distinct = (i != j) && (j != k) && (i != k);
            conf[(i * NN + j) * NN + k] = distinct ? sg : 0.f;
        }
    } else if (bid == 512) {
        // ---- intervention MLP, d-parallel coalesced loads
        __shared__ float in_s[DD + 1];
        __shared__ float4 red[8][64];
        __shared__ float h_s[HH];
        const int node = inode[0];
        if (tid < DD) in_s[tid] = x[node * DD + tid];
        if (tid == DD) in_s[DD] = ival[0];
        __syncthreads();
        {
            const int c4 = tid & 63;
            const int dg = tid >> 6;
            const float4* W1v = (const float4*)ipW1;
            float4 acc = {0.f, 0.f, 0.f, 0.f};
#pragma unroll 8
            for (int r = 0; r < 32; ++r) {
                const int d = dg * 32 + r;
                const float xv = in_s[d];
                const float4 w = W1v[d * 64 + c4];
                acc.x += xv * w.x; acc.y += xv * w.y;
                acc.z += xv * w.z; acc.w += xv * w.w;
            }
            if (dg == 0) {
                const float xv = in_s[128];
                const float4 w = W1v[128 * 64 + c4];
                acc.x += xv * w.x; acc.y += xv * w.y;
                acc.z += xv * w.z; acc.w += xv * w.w;
            }
            red[dg][c4] = acc;
        }
        __syncthreads();
        if (tid < 64) {
            const float4 r0 = red[0][tid], r1 = red[1][tid];
            const float4 r2 = red[2][tid], r3 = red[3][tid];
            const float4 b = ((const float4*)ipb1)[tid];
            float4 h;
            h.x = fmaxf(r0.x + r1.x + r2.x + r3.x + b.x, 0.f);
            h.y = fmaxf(r0.y + r1.y + r2.y + r3.y + b.y, 0.f);
            h.z = fmaxf(r0.z + r1.z + r2.z + r3.z + b.z, 0.f);
            h.w = fmaxf(r0.w + r1.w + r2.w + r3.w + b.w, 0.f);
            ((float4*)h_s)[tid] = h;
        }
        __syncthreads();
        {
            const int c4 = tid & 31;
            const int ug = tid >> 5;
            const float4* W2v = (const float4*)ipW2;
            float4 acc = {0.f, 0.f, 0.f, 0.f};
#pragma unroll 8
            for (int r = 0; r < 32; ++r) {
                const int uu = ug * 32 + r;
                const float hv = h_s[uu];
                const float4 w = W2v[uu * 32 + c4];
                acc.x += hv * w.x; acc.y += hv * w.y;
                acc.z += hv * w.z; acc.w += hv * w.w;
            }
            ((float4*)red)[ug * 32 + c4] = acc;
        }
        __syncthreads();
        if (tid < 32) {
            float4 s = ((const float4*)ipb2)[tid];
#pragma unroll
            for (int g = 0; g < 8; ++g) {
                const float4 r = ((const float4*)red)[g * 32 + tid];
                s.x += r.x; s.y += r.y; s.z += r.z; s.w += r.w;
            }
            ((float4*)(out3 + node * DD))[tid] = s;
        }
    } else {
        // ---- out3 copy (rows != node), 2 blocks x 32 rows
        const int node = inode[0];
        const int n = (bid - 513) * 32 + (tid >> 3);
        const int part = tid & 7;
        if (n != node) {
            const float4* src = (const float4*)(x + n * DD);
            float4* dst = (float4*)(out3 + n * DD);
#pragma unroll
            for (int e = 0; e < 4; ++e) dst[part * 4 + e] = src[part * 4 + e];
        }
    }
}

extern "C" void kernel_launch(void* const* d_in, const int* in_sizes, int n_in,
                              void* d_out, int out_size, void* d_ws, size_t ws_size,
                              hipStream_t stream) {
    const float* x    = (const float*)d_in[0];
    const int*   node = (const int*)d_in[1];
    const float* ival = (const float*)d_in[2];
    const float* cdW1 = (const float*)d_in[3];
    const float* cdb1 = (const float*)d_in[4];
    const float* cdW2 = (const float*)d_in[5];
    const float* cdb2 = (const float*)d_in[6];
    const float* cdW3 = (const float*)d_in[7];
    const float* cdb3 = (const float*)d_in[8];
    const float* cfW1 = (const float*)d_in[9];
    const float* cfb1 = (const float*)d_in[10];
    const float* cfW2 = (const float*)d_in[11];
    const float* cfb2 = (const float*)d_in[12];
    const float* ipW1 = (const float*)d_in[13];
    const float* ipb1 = (const float*)d_in[14];
    const float* ipW2 = (const float*)d_in[15];
    const float* ipb2 = (const float*)d_in[16];

    float* out    = (float*)d_out;
    float* causal = out;                           // 4096
    float* conf   = out + NN * NN;                 // 262144
    float* out3   = out + NN * NN + NN * NN * NN;  // 8192
    float* wsf    = (float*)d_ws;

    k_stage<<<dim3(328), dim3(512), 0, stream>>>(
        x, node, cdW1, cdb1, cdW2, cfW1, cfb1, wsf, out3);
    k_main<<<dim3(515), dim3(256), 0, stream>>>(
        wsf, x, node, ival, cdb2, cdW3, cdb3, cfW2, cfb2,
        ipW1, ipb1, ipW2, ipb2, causal, conf, out3);
    // MEASUREMENT: 5 empty nodes. Per-node overhead L = (dur - 31.3)/5.
    for (int rep = 0; rep < 5; ++rep) {
        k_empty<<<dim3(1), dim3(64), 0, stream>>>();
    }
}

// Round 14
// 31.231 us; speedup vs baseline: 3.6984x; 1.2374x over previous
//
#include <hip/hip_runtime.h>
#include <hip/hip_fp16.h>
#include <math.h>

#define NN 64
#define DD 128
#define HH 256

typedef __attribute__((ext_vector_type(8))) short short8;
typedef __attribute__((ext_vector_type(4))) float f32x4;

// ws layout (floats):
//   P    [64][256] @ 0        f32 (x @ cdW1[0:128] + cdb1)      — pairs
//   Q    [64][256] @ 16384    f32 (x @ cdW1[128:256])           — pairs
//   A16  [64][256] @ 32768    f16 rows (x @ cfW1[0:128] + cfb1) — triple
//   B16  [64][256] @ 40960    f16 rows (x @ cfW1[128:256])      — triple
//   C16q [32 g][64 k]uint4 @ 49152  f16, entry(g,k) = d 8g..8g+7 of node k
//   w16  [256] f16 @ 57344    (cfW2)
//   W2T  bf16 [128 c][256 t] @ 81920 (cdW2^T, bf16)             — pairs

__device__ __forceinline__ short f2bf(float f) {
    unsigned u = __float_as_uint(f);
    unsigned r = (u + 0x7fffu + ((u >> 16) & 1u)) >> 16;
    return (short)r;
}
__device__ __forceinline__ unsigned pack2(float lo, float hi) {
    __half2 h = __floats2half2_rn(lo, hi);
    return __builtin_bit_cast(unsigned, h);
}
__device__ __forceinline__ __half2 uh2(unsigned u) {
    return __builtin_bit_cast(__half2, u);
}
// packed ReLU: t * (t > 0)  (no __hmax2 in ROCm 7.2 headers)
__device__ __forceinline__ __half2 relu2(__half2 t, __half2 z2) {
    return __hmul2(t, __hgt2(t, z2));
}

// Kernel A, 512 thr, grid 328. Blocks 0..319: projection p=bid>>6, node n=bid&63.
// Blocks 320..327: cdW2 -> W2T bf16 transpose (one latency round).
__global__ __launch_bounds__(512) void k_stage(
    const float* __restrict__ x, const int* __restrict__ inode,
    const float* __restrict__ cdW1, const float* __restrict__ cdb1,
    const float* __restrict__ cdW2, const float* __restrict__ cfW2,
    const float* __restrict__ cfW1, const float* __restrict__ cfb1,
    float* __restrict__ ws, float* __restrict__ out3)
{
    const int bid = blockIdx.x;
    const int tid = threadIdx.x;
    if (bid < 320) {
        __shared__ float xs[DD];
        __shared__ float4 red[8][64];
        const int p = bid >> 6;
        const int n = bid & 63;
        if (tid < DD) xs[tid] = x[n * DD + tid];
        __syncthreads();
        const int c4 = tid & 63;   // output column group (4 cols)
        const int dg = tid >> 6;   // 0..7, 16 d's each
        const float* Wp = (p == 0) ? cdW1
                        : (p == 1) ? (cdW1 + DD * HH)
                                   : (cfW1 + (p - 2) * DD * HH);
        const float4* Wp4 = (const float4*)Wp;
        float4 w[16];
#pragma unroll
        for (int q = 0; q < 16; ++q) w[q] = Wp4[(dg * 16 + q) * 64 + c4];
        float4 acc = {0.f, 0.f, 0.f, 0.f};
#pragma unroll
        for (int q = 0; q < 16; ++q) {
            const float xv = xs[dg * 16 + q];
            acc.x += xv * w[q].x; acc.y += xv * w[q].y;
            acc.z += xv * w[q].z; acc.w += xv * w[q].w;
        }
        red[dg][c4] = acc;
        __syncthreads();
        if (tid < 64) {
            float4 s = {0.f, 0.f, 0.f, 0.f};
#pragma unroll
            for (int g = 0; g < 8; ++g) {
                const float4 r = red[g][tid];
                s.x += r.x; s.y += r.y; s.z += r.z; s.w += r.w;
            }
            if (p == 0) {
                const float4 b = ((const float4*)cdb1)[tid];
                s.x += b.x; s.y += b.y; s.z += b.z; s.w += b.w;
                ((float4*)(ws))[n * 64 + tid] = s;
            } else if (p == 1) {
                ((float4*)(ws + 16384))[n * 64 + tid] = s;
            } else if (p == 2) {
                const float4 b = ((const float4*)cfb1)[tid];
                s.x += b.x; s.y += b.y; s.z += b.z; s.w += b.w;
                ((uint2*)(ws + 32768))[n * 64 + tid] =
                    make_uint2(pack2(s.x, s.y), pack2(s.z, s.w));
            } else if (p == 3) {
                ((uint2*)(ws + 40960))[n * 64 + tid] =
                    make_uint2(pack2(s.x, s.y), pack2(s.z, s.w));
            } else {
                // C16q: thread t holds d = 4t..4t+3 of node n -> uint2 at
                // uint2-index ((t>>1)*64 + n)*2 + (t&1)
                ((uint2*)(ws + 49152))[(((tid >> 1) * 64 + n) << 1) + (tid & 1)] =
                    make_uint2(pack2(s.x, s.y), pack2(s.z, s.w));
            }
        }
        // w16 staging piggybacked on block p==4,n==0 (threads 128..191, idle now)
        if (bid == 256 && tid >= 128 && tid < 192) {
            const int u = tid - 128;
            const float4 w4 = ((const float4*)cfW2)[u];
            ((uint2*)(ws + 57344))[u] =
                make_uint2(pack2(w4.x, w4.y), pack2(w4.z, w4.w));
        }
    } else {
        // W2T[c][t] = bf16(cdW2[t][c]); 16 c's per block, 32 threads per c
        unsigned short* W2T = (unsigned short*)(ws + 81920);
        const int c  = (bid - 320) * 16 + (tid >> 5);
        const int t0 = (tid & 31) * 8;
        float v[8];
#pragma unroll
        for (int e = 0; e < 8; ++e) v[e] = cdW2[(t0 + e) * 128 + c];
        unsigned short pk[8];
#pragma unroll
        for (int e = 0; e < 8; ++e) pk[e] = (unsigned short)f2bf(v[e]);
        *(ulong2*)(W2T + c * HH + t0) = *(ulong2*)pk;
    }
}

// Kernel B, 256 thr, grid 515.
__global__ __launch_bounds__(256) void k_main(
    const float* __restrict__ ws, const float* __restrict__ x,
    const int* __restrict__ inode, const float* __restrict__ ival,
    const float* __restrict__ cdb2, const float* __restrict__ cdW3,
    const float* __restrict__ cdb3, const float* __restrict__ cfb2,
    const float* __restrict__ ipW1, const float* __restrict__ ipb1,
    const float* __restrict__ ipW2, const float* __restrict__ ipb2,
    float* __restrict__ causal, float* __restrict__ conf,
    float* __restrict__ out3)
{
    const int bid = blockIdx.x;
    const int tid = threadIdx.x;
    if (bid < 256) {
        // ---- causal pairs via bf16 MFMA, no LDS main loop
        const int i  = bid >> 2;
        const int j0 = (bid & 3) * 16;
        const int wid  = tid >> 6;
        const int lane = tid & 63;
        const int lo = lane & 15;
        const int hi = lane >> 4;
        const int n0 = wid * 32;

        const float* Prow = ws + i * HH;
        const float* Qrow = ws + 16384 + (j0 + lo) * HH;
        const unsigned short* W2T = (const unsigned short*)(ws + 81920);

        f32x4 acc0 = {0.f, 0.f, 0.f, 0.f};
        f32x4 acc1 = {0.f, 0.f, 0.f, 0.f};
#pragma unroll
        for (int step = 0; step < 8; ++step) {
            const int kb = step * 32 + hi * 8;
            const float4 pa = *(const float4*)(Prow + kb);
            const float4 pb = *(const float4*)(Prow + kb + 4);
            const float4 qa = *(const float4*)(Qrow + kb);
            const float4 qb = *(const float4*)(Qrow + kb + 4);
            short8 af;
            af[0] = f2bf(fmaxf(pa.x + qa.x, 0.f));
            af[1] = f2bf(fmaxf(pa.y + qa.y, 0.f));
            af[2] = f2bf(fmaxf(pa.z + qa.z, 0.f));
            af[3] = f2bf(fmaxf(pa.w + qa.w, 0.f));
            af[4] = f2bf(fmaxf(pb.x + qb.x, 0.f));
            af[5] = f2bf(fmaxf(pb.y + qb.y, 0.f));
            af[6] = f2bf(fmaxf(pb.z + qb.z, 0.f));
            af[7] = f2bf(fmaxf(pb.w + qb.w, 0.f));
            const short8 b0 = *(const short8*)(W2T + (n0 + lo) * HH + kb);
            const short8 b1 = *(const short8*)(W2T + (n0 + 16 + lo) * HH + kb);
            acc0 = __builtin_amdgcn_mfma_f32_16x16x32_bf16(af, b0, acc0, 0, 0, 0);
            acc1 = __builtin_amdgcn_mfma_f32_16x16x32_bf16(af, b1, acc1, 0, 0, 0);
        }
        const int c0 = n0 + lo;
        const int c1 = n0 + 16 + lo;
        const float b2a = cdb2[c0], b2b = cdb2[c1];
        const float w3a = cdW3[c0], w3b = cdW3[c1];
        float pr[4];
#pragma unroll
        for (int r = 0; r < 4; ++r) {
            pr[r] = fmaxf(acc0[r] + b2a, 0.f) * w3a
                  + fmaxf(acc1[r] + b2b, 0.f) * w3b;
        }
#pragma unroll
        for (int m = 1; m <= 8; m <<= 1) {
#pragma unroll
            for (int r = 0; r < 4; ++r) pr[r] += __shfl_xor(pr[r], m, 64);
        }
        __shared__ float zp[4][16];
        if (lo == 0) {
#pragma unroll
            for (int r = 0; r < 4; ++r) zp[wid][hi * 4 + r] = pr[r];
        }
        __syncthreads();
        if (tid < 16) {
            const float z = zp[0][tid] + zp[1][tid] + zp[2][tid] + zp[3][tid] + cdb3[0];
            const float sg = 1.f / (1.f + expf(-z));
            const int j = j0 + tid;
            causal[i * NN + j] = (i == j) ? 0.f : sg;
        }
    } else if (bid < 512) {
        // ---- confounder triples, packed-f16, zero-LDS
        const int u = bid - 256;
        const int i  = u >> 2;
        const int j0 = (u & 3) * 16;
        const int k   = tid & 63;
        const int jj2 = tid >> 6;
        const uint4* C16v = (const uint4*)(ws + 49152);          // [g*64 + k]
        const uint4* A16v = (const uint4*)(ws + 32768) + i * 32; // row i, 32 entries
        const uint4* B16b = (const uint4*)(ws + 40960);          // rows of 32
        const uint4* W16v = (const uint4*)(ws + 57344);          // 32 entries
        const __half2 z2 = __float2half2_rn(0.f);
        float accf[4] = {0.f, 0.f, 0.f, 0.f};
        for (int ch = 0; ch < 8; ++ch) {   // 4 g-groups per chunk, 32 total
            uint4 cr[4], av[4], wr[4];
#pragma unroll
            for (int q = 0; q < 4; ++q) {
                const int g = ch * 4 + q;
                cr[q] = C16v[g * 64 + k];   // coalesced over k-lanes
                av[q] = A16v[g];            // wave-uniform
                wr[q] = W16v[g];            // wave-uniform
            }
#pragma unroll
            for (int p = 0; p < 4; ++p) {
                const int j = j0 + p * 4 + jj2;
                const uint4* Bv = B16b + j * 32;
                uint4 bv[4];
#pragma unroll
                for (int q = 0; q < 4; ++q) bv[q] = Bv[ch * 4 + q];
                __half2 acc2 = z2;
#pragma unroll
                for (int q = 0; q < 4; ++q) {
                    {
                        const __half2 t = __hadd2(__hadd2(uh2(av[q].x), uh2(bv[q].x)), uh2(cr[q].x));
                        acc2 = __hfma2(relu2(t, z2), uh2(wr[q].x), acc2);
                    }
                    {
                        const __half2 t = __hadd2(__hadd2(uh2(av[q].y), uh2(bv[q].y)), uh2(cr[q].y));
                        acc2 = __hfma2(relu2(t, z2), uh2(wr[q].y), acc2);
                    }
                    {
                        const __half2 t = __hadd2(__hadd2(uh2(av[q].z), uh2(bv[q].z)), uh2(cr[q].z));
                        acc2 = __hfma2(relu2(t, z2), uh2(wr[q].z), acc2);
                    }
                    {
                        const __half2 t = __hadd2(__hadd2(uh2(av[q].w), uh2(bv[q].w)), uh2(cr[q].w));
                        acc2 = __hfma2(relu2(t, z2), uh2(wr[q].w), acc2);
                    }
                }
                accf[p] += __low2float(acc2) + __high2float(acc2);
            }
        }
        const float b2 = cfb2[0];
#pragma unroll
        for (int p = 0; p < 4; ++p) {
            const int j = j0 + p * 4 + jj2;
            const float z = accf[p] + b2;
            const float sg = 1.f / (1.f + expf(-z));
            const bool distinct = (i != j) && (j != k) && (i != k);
            conf[(i * NN + j) * NN + k] = distinct ? sg : 0.f;
        }
    } else if (bid == 512) {
        // ---- intervention MLP, d-parallel coalesced loads
        __shared__ float in_s[DD + 1];
        __shared__ float4 red[8][64];
        __shared__ float h_s[HH];
        const int node = inode[0];
        if (tid < DD) in_s[tid] = x[node * DD + tid];
        if (tid == DD) in_s[DD] = ival[0];
        __syncthreads();
        {
            const int c4 = tid & 63;
            const int dg = tid >> 6;
            const float4* W1v = (const float4*)ipW1;
            float4 acc = {0.f, 0.f, 0.f, 0.f};
#pragma unroll 8
            for (int r = 0; r < 32; ++r) {
                const int d = dg * 32 + r;
                const float xv = in_s[d];
                const float4 w = W1v[d * 64 + c4];
                acc.x += xv * w.x; acc.y += xv * w.y;
                acc.z += xv * w.z; acc.w += xv * w.w;
            }
            if (dg == 0) {
                const float xv = in_s[128];
                const float4 w = W1v[128 * 64 + c4];
                acc.x += xv * w.x; acc.y += xv * w.y;
                acc.z += xv * w.z; acc.w += xv * w.w;
            }
            red[dg][c4] = acc;
        }
        __syncthreads();
        if (tid < 64) {
            const float4 r0 = red[0][tid], r1 = red[1][tid];
            const float4 r2 = red[2][tid], r3 = red[3][tid];
            const float4 b = ((const float4*)ipb1)[tid];
            float4 h;
            h.x = fmaxf(r0.x + r1.x + r2.x + r3.x + b.x, 0.f);
            h.y = fmaxf(r0.y + r1.y + r2.y + r3.y + b.y, 0.f);
            h.z = fmaxf(r0.z + r1.z + r2.z + r3.z + b.z, 0.f);
            h.w = fmaxf(r0.w + r1.w + r2.w + r3.w + b.w, 0.f);
            ((float4*)h_s)[tid] = h;
        }
        __syncthreads();
        {
            const int c4 = tid & 31;
            const int ug = tid >> 5;
            const float4* W2v = (const float4*)ipW2;
            float4 acc = {0.f, 0.f, 0.f, 0.f};
#pragma unroll 8
            for (int r = 0; r < 32; ++r) {
                const int uu = ug * 32 + r;
                const float hv = h_s[uu];
                const float4 w = W2v[uu * 32 + c4];
                acc.x += hv * w.x; acc.y += hv * w.y;
                acc.z += hv * w.z; acc.w += hv * w.w;
            }
            ((float4*)red)[ug * 32 + c4] = acc;
        }
        __syncthreads();
        if (tid < 32) {
            float4 s = ((const float4*)ipb2)[tid];
#pragma unroll
            for (int g = 0; g < 8; ++g) {
                const float4 r = ((const float4*)red)[g * 32 + tid];
                s.x += r.x; s.y += r.y; s.z += r.z; s.w += r.w;
            }
            ((float4*)(out3 + node * DD))[tid] = s;
        }
    } else {
        // ---- out3 copy (rows != node), 2 blocks x 32 rows
        const int node = inode[0];
        const int n = (bid - 513) * 32 + (tid >> 3);
        const int part = tid & 7;
        if (n != node) {
            const float4* src = (const float4*)(x + n * DD);
            float4* dst = (float4*)(out3 + n * DD);
#pragma unroll
            for (int e = 0; e < 4; ++e) dst[part * 4 + e] = src[part * 4 + e];
        }
    }
}

extern "C" void kernel_launch(void* const* d_in, const int* in_sizes, int n_in,
                              void* d_out, int out_size, void* d_ws, size_t ws_size,
                              hipStream_t stream) {
    const float* x    = (const float*)d_in[0];
    const int*   node = (const int*)d_in[1];
    const float* ival = (const float*)d_in[2];
    const float* cdW1 = (const float*)d_in[3];
    const float* cdb1 = (const float*)d_in[4];
    const float* cdW2 = (const float*)d_in[5];
    const float* cdb2 = (const float*)d_in[6];
    const float* cdW3 = (const float*)d_in[7];
    const float* cdb3 = (const float*)d_in[8];
    const float* cfW1 = (const float*)d_in[9];
    const float* cfb1 = (const float*)d_in[10];
    const float* cfW2 = (const float*)d_in[11];
    const float* cfb2 = (const float*)d_in[12];
    const float* ipW1 = (const float*)d_in[13];
    const float* ipb1 = (const float*)d_in[14];
    const float* ipW2 = (const float*)d_in[15];
    const float* ipb2 = (const float*)d_in[16];

    float* out    = (float*)d_out;
    float* causal = out;                           // 4096
    float* conf   = out + NN * NN;                 // 262144
    float* out3   = out + NN * NN + NN * NN * NN;  // 8192
    float* wsf    = (float*)d_ws;

    k_stage<<<dim3(328), dim3(512), 0, stream>>>(
        x, node, cdW1, cdb1, cdW2, cfW2, cfW1, cfb1, wsf, out3);
    k_main<<<dim3(515), dim3(256), 0, stream>>>(
        wsf, x, node, ival, cdb2, cdW3, cdb3, cfb2,
        ipW1, ipb1, ipW2, ipb2, causal, conf, out3);
}

// Round 15
// 25.602 us; speedup vs baseline: 4.5116x; 1.2199x over previous
//
#include <hip/hip_runtime.h>
#include <hip/hip_fp16.h>
#include <math.h>

#define NN 64
#define DD 128
#define HH 256

typedef __attribute__((ext_vector_type(8))) short short8;
typedef __attribute__((ext_vector_type(4))) float f32x4;

// ws layout (floats):
//   P    [64][256] @ 0        f32 (x @ cdW1[0:128] + cdb1)      — pairs
//   Q    [64][256] @ 16384    f32 (x @ cdW1[128:256])           — pairs
//   A16  [64][256] @ 32768    f16 rows (x @ cfW1[0:128] + cfb1) — triple
//   B16  [64][256] @ 40960    f16 rows (x @ cfW1[128:256])      — triple
//   C16q [32 g][64 k]uint4 @ 49152  f16, entry(g,k) = d 8g..8g+7 of node k
//   w16  [256] f16 @ 57344    (cfW2)
//   W2T  bf16 [128 c][256 t] @ 81920 (cdW2^T, bf16)             — pairs

__device__ __forceinline__ short f2bf(float f) {
    unsigned u = __float_as_uint(f);
    unsigned r = (u + 0x7fffu + ((u >> 16) & 1u)) >> 16;
    return (short)r;
}
__device__ __forceinline__ unsigned pack2(float lo, float hi) {
    __half2 h = __floats2half2_rn(lo, hi);
    return __builtin_bit_cast(unsigned, h);
}
__device__ __forceinline__ __half2 uh2(unsigned u) {
    return __builtin_bit_cast(__half2, u);
}
// packed ReLU: t * (t > 0)  (no __hmax2 in ROCm 7.2 headers)
__device__ __forceinline__ __half2 relu2(__half2 t, __half2 z2) {
    return __hmul2(t, __hgt2(t, z2));
}

// Kernel A, 512 thr, grid 331.
//   0..319 : projection p=bid>>6, node n=bid&63
//   320..327: cdW2 -> W2T bf16 transpose
//   328    : intervention MLP (512-thread version)
//   329,330: out3 row copies
__global__ __launch_bounds__(512) void k_stage(
    const float* __restrict__ x, const int* __restrict__ inode,
    const float* __restrict__ ival,
    const float* __restrict__ cdW1, const float* __restrict__ cdb1,
    const float* __restrict__ cdW2, const float* __restrict__ cfW2,
    const float* __restrict__ cfW1, const float* __restrict__ cfb1,
    const float* __restrict__ ipW1, const float* __restrict__ ipb1,
    const float* __restrict__ ipW2, const float* __restrict__ ipb2,
    float* __restrict__ ws, float* __restrict__ out3)
{
    __shared__ float xs[136];        // proj: x row; MLP: [x[node], v]
    __shared__ float4 red[8][64];    // proj/MLP-l1 reduce; MLP-l2 as [16][32]
    __shared__ float h_s[HH];        // MLP hidden
    const int bid = blockIdx.x;
    const int tid = threadIdx.x;
    if (bid < 320) {
        const int p = bid >> 6;
        const int n = bid & 63;
        if (tid < DD) xs[tid] = x[n * DD + tid];
        __syncthreads();
        const int c4 = tid & 63;   // output column group (4 cols)
        const int dg = tid >> 6;   // 0..7, 16 d's each
        const float* Wp = (p == 0) ? cdW1
                        : (p == 1) ? (cdW1 + DD * HH)
                                   : (cfW1 + (p - 2) * DD * HH);
        const float4* Wp4 = (const float4*)Wp;
        float4 w[16];
#pragma unroll
        for (int q = 0; q < 16; ++q) w[q] = Wp4[(dg * 16 + q) * 64 + c4];
        float4 acc = {0.f, 0.f, 0.f, 0.f};
#pragma unroll
        for (int q = 0; q < 16; ++q) {
            const float xv = xs[dg * 16 + q];
            acc.x += xv * w[q].x; acc.y += xv * w[q].y;
            acc.z += xv * w[q].z; acc.w += xv * w[q].w;
        }
        red[dg][c4] = acc;
        __syncthreads();
        if (tid < 64) {
            float4 s = {0.f, 0.f, 0.f, 0.f};
#pragma unroll
            for (int g = 0; g < 8; ++g) {
                const float4 r = red[g][tid];
                s.x += r.x; s.y += r.y; s.z += r.z; s.w += r.w;
            }
            if (p == 0) {
                const float4 b = ((const float4*)cdb1)[tid];
                s.x += b.x; s.y += b.y; s.z += b.z; s.w += b.w;
                ((float4*)(ws))[n * 64 + tid] = s;
            } else if (p == 1) {
                ((float4*)(ws + 16384))[n * 64 + tid] = s;
            } else if (p == 2) {
                const float4 b = ((const float4*)cfb1)[tid];
                s.x += b.x; s.y += b.y; s.z += b.z; s.w += b.w;
                ((uint2*)(ws + 32768))[n * 64 + tid] =
                    make_uint2(pack2(s.x, s.y), pack2(s.z, s.w));
            } else if (p == 3) {
                ((uint2*)(ws + 40960))[n * 64 + tid] =
                    make_uint2(pack2(s.x, s.y), pack2(s.z, s.w));
            } else {
                // C16q: thread t holds d = 4t..4t+3 of node n
                ((uint2*)(ws + 49152))[(((tid >> 1) * 64 + n) << 1) + (tid & 1)] =
                    make_uint2(pack2(s.x, s.y), pack2(s.z, s.w));
            }
        }
        // w16 staging piggybacked on block p==4,n==0 (threads 128..191)
        if (bid == 256 && tid >= 128 && tid < 192) {
            const int u = tid - 128;
            const float4 w4 = ((const float4*)cfW2)[u];
            ((uint2*)(ws + 57344))[u] =
                make_uint2(pack2(w4.x, w4.y), pack2(w4.z, w4.w));
        }
    } else if (bid < 328) {
        // W2T[c][t] = bf16(cdW2[t][c]); 16 c's per block, 32 threads per c
        unsigned short* W2T = (unsigned short*)(ws + 81920);
        const int c  = (bid - 320) * 16 + (tid >> 5);
        const int t0 = (tid & 31) * 8;
        float v[8];
#pragma unroll
        for (int e = 0; e < 8; ++e) v[e] = cdW2[(t0 + e) * 128 + c];
        unsigned short pk[8];
#pragma unroll
        for (int e = 0; e < 8; ++e) pk[e] = (unsigned short)f2bf(v[e]);
        *(ulong2*)(W2T + c * HH + t0) = *(ulong2*)pk;
    } else if (bid == 328) {
        // ---- intervention MLP, 512 threads
        const int node = inode[0];
        if (tid < DD) xs[tid] = x[node * DD + tid];
        if (tid == DD) xs[DD] = ival[0];
        __syncthreads();
        {   // layer 1: 256 cols, K=129; dg covers 16 d's
            const int c4 = tid & 63;
            const int dg = tid >> 6;   // 0..7
            const float4* W1v = (const float4*)ipW1;
            float4 acc = {0.f, 0.f, 0.f, 0.f};
#pragma unroll
            for (int r = 0; r < 16; ++r) {
                const int d = dg * 16 + r;
                const float xv = xs[d];
                const float4 w = W1v[d * 64 + c4];
                acc.x += xv * w.x; acc.y += xv * w.y;
                acc.z += xv * w.z; acc.w += xv * w.w;
            }
            if (dg == 0) {
                const float xv = xs[128];
                const float4 w = W1v[128 * 64 + c4];
                acc.x += xv * w.x; acc.y += xv * w.y;
                acc.z += xv * w.z; acc.w += xv * w.w;
            }
            red[dg][c4] = acc;
        }
        __syncthreads();
        if (tid < 64) {
            float4 s = ((const float4*)ipb1)[tid];
#pragma unroll
            for (int g = 0; g < 8; ++g) {
                const float4 r = red[g][tid];
                s.x += r.x; s.y += r.y; s.z += r.z; s.w += r.w;
            }
            float4 h;
            h.x = fmaxf(s.x, 0.f); h.y = fmaxf(s.y, 0.f);
            h.z = fmaxf(s.z, 0.f); h.w = fmaxf(s.w, 0.f);
            ((float4*)h_s)[tid] = h;
        }
        __syncthreads();
        {   // layer 2: 128 cols, K=256; ug covers 16 u's
            const int c4 = tid & 31;
            const int ug = tid >> 5;   // 0..15
            const float4* W2v = (const float4*)ipW2;
            float4 acc = {0.f, 0.f, 0.f, 0.f};
#pragma unroll
            for (int r = 0; r < 16; ++r) {
                const int uu = ug * 16 + r;
                const float hv = h_s[uu];
                const float4 w = W2v[uu * 32 + c4];
                acc.x += hv * w.x; acc.y += hv * w.y;
                acc.z += hv * w.z; acc.w += hv * w.w;
            }
            ((float4*)red)[ug * 32 + c4] = acc;
        }
        __syncthreads();
        if (tid < 32) {
            float4 s = ((const float4*)ipb2)[tid];
#pragma unroll
            for (int g = 0; g < 16; ++g) {
                const float4 r = ((const float4*)red)[g * 32 + tid];
                s.x += r.x; s.y += r.y; s.z += r.z; s.w += r.w;
            }
            ((float4*)(out3 + node * DD))[tid] = s;
        }
    } else {
        // ---- out3 copies (rows != node), 32 rows per block, 16 thr/row
        const int node = inode[0];
        const int n = (bid - 329) * 32 + (tid >> 4);
        const int part = tid & 15;
        if (n != node) {
            const float4* src = (const float4*)(x + n * DD);
            float4* dst = (float4*)(out3 + n * DD);
            dst[part * 2]     = src[part * 2];
            dst[part * 2 + 1] = src[part * 2 + 1];
        }
    }
}

// Kernel B, 256 thr, grid 768.
//   bid <  256: pairs MFMA unit (i=bid>>2, j0=(bid&3)*16)
//   bid >= 256: triple unit, 512 blocks x 8 j's (i=u>>3, j08=(u&7)*8)
__global__ __launch_bounds__(256) void k_main(
    const float* __restrict__ ws,
    const float* __restrict__ cdb2, const float* __restrict__ cdW3,
    const float* __restrict__ cdb3, const float* __restrict__ cfb2,
    float* __restrict__ causal, float* __restrict__ conf)
{
    const int bid = blockIdx.x;
    const int tid = threadIdx.x;
    if (bid < 256) {
        // ---- causal pairs via bf16 MFMA, no LDS main loop
        const int i  = bid >> 2;
        const int j0 = (bid & 3) * 16;
        const int wid  = tid >> 6;
        const int lane = tid & 63;
        const int lo = lane & 15;
        const int hi = lane >> 4;
        const int n0 = wid * 32;

        const float* Prow = ws + i * HH;
        const float* Qrow = ws + 16384 + (j0 + lo) * HH;
        const unsigned short* W2T = (const unsigned short*)(ws + 81920);

        f32x4 acc0 = {0.f, 0.f, 0.f, 0.f};
        f32x4 acc1 = {0.f, 0.f, 0.f, 0.f};
#pragma unroll
        for (int step = 0; step < 8; ++step) {
            const int kb = step * 32 + hi * 8;
            const float4 pa = *(const float4*)(Prow + kb);
            const float4 pb = *(const float4*)(Prow + kb + 4);
            const float4 qa = *(const float4*)(Qrow + kb);
            const float4 qb = *(const float4*)(Qrow + kb + 4);
            short8 af;
            af[0] = f2bf(fmaxf(pa.x + qa.x, 0.f));
            af[1] = f2bf(fmaxf(pa.y + qa.y, 0.f));
            af[2] = f2bf(fmaxf(pa.z + qa.z, 0.f));
            af[3] = f2bf(fmaxf(pa.w + qa.w, 0.f));
            af[4] = f2bf(fmaxf(pb.x + qb.x, 0.f));
            af[5] = f2bf(fmaxf(pb.y + qb.y, 0.f));
            af[6] = f2bf(fmaxf(pb.z + qb.z, 0.f));
            af[7] = f2bf(fmaxf(pb.w + qb.w, 0.f));
            const short8 b0 = *(const short8*)(W2T + (n0 + lo) * HH + kb);
            const short8 b1 = *(const short8*)(W2T + (n0 + 16 + lo) * HH + kb);
            acc0 = __builtin_amdgcn_mfma_f32_16x16x32_bf16(af, b0, acc0, 0, 0, 0);
            acc1 = __builtin_amdgcn_mfma_f32_16x16x32_bf16(af, b1, acc1, 0, 0, 0);
        }
        const int c0 = n0 + lo;
        const int c1 = n0 + 16 + lo;
        const float b2a = cdb2[c0], b2b = cdb2[c1];
        const float w3a = cdW3[c0], w3b = cdW3[c1];
        float pr[4];
#pragma unroll
        for (int r = 0; r < 4; ++r) {
            pr[r] = fmaxf(acc0[r] + b2a, 0.f) * w3a
                  + fmaxf(acc1[r] + b2b, 0.f) * w3b;
        }
#pragma unroll
        for (int m = 1; m <= 8; m <<= 1) {
#pragma unroll
            for (int r = 0; r < 4; ++r) pr[r] += __shfl_xor(pr[r], m, 64);
        }
        __shared__ float zp[4][16];
        if (lo == 0) {
#pragma unroll
            for (int r = 0; r < 4; ++r) zp[wid][hi * 4 + r] = pr[r];
        }
        __syncthreads();
        if (tid < 16) {
            const float z = zp[0][tid] + zp[1][tid] + zp[2][tid] + zp[3][tid] + cdb3[0];
            const float sg = 1.f / (1.f + expf(-z));
            const int j = j0 + tid;
            causal[i * NN + j] = (i == j) ? 0.f : sg;
        }
    } else {
        // ---- confounder triples, packed-f16, zero-LDS, 8 j's per block
        const int u = bid - 256;
        const int i   = u >> 3;
        const int j08 = (u & 7) * 8;
        const int k   = tid & 63;
        const int jj2 = tid >> 6;
        const uint4* C16v = (const uint4*)(ws + 49152);          // [g*64 + k]
        const uint4* A16v = (const uint4*)(ws + 32768) + i * 32; // row i
        const uint4* B16b = (const uint4*)(ws + 40960);          // rows of 32
        const uint4* W16v = (const uint4*)(ws + 57344);          // 32 entries
        const __half2 z2 = __float2half2_rn(0.f);
        float accf[2] = {0.f, 0.f};
        for (int ch = 0; ch < 8; ++ch) {   // 4 g-groups per chunk, 32 total
            uint4 cr[4], av[4], wr[4];
#pragma unroll
            for (int q = 0; q < 4; ++q) {
                const int g = ch * 4 + q;
                cr[q] = C16v[g * 64 + k];   // coalesced over k-lanes
                av[q] = A16v[g];            // wave-uniform
                wr[q] = W16v[g];            // wave-uniform
            }
#pragma unroll
            for (int p = 0; p < 2; ++p) {
                const int j = j08 + p * 4 + jj2;
                const uint4* Bv = B16b + j * 32;
                uint4 bv[4];
#pragma unroll
                for (int q = 0; q < 4; ++q) bv[q] = Bv[ch * 4 + q];
                __half2 acc2 = z2;
#pragma unroll
                for (int q = 0; q < 4; ++q) {
                    {
                        const __half2 t = __hadd2(__hadd2(uh2(av[q].x), uh2(bv[q].x)), uh2(cr[q].x));
                        acc2 = __hfma2(relu2(t, z2), uh2(wr[q].x), acc2);
                    }
                    {
                        const __half2 t = __hadd2(__hadd2(uh2(av[q].y), uh2(bv[q].y)), uh2(cr[q].y));
                        acc2 = __hfma2(relu2(t, z2), uh2(wr[q].y), acc2);
                    }
                    {
                        const __half2 t = __hadd2(__hadd2(uh2(av[q].z), uh2(bv[q].z)), uh2(cr[q].z));
                        acc2 = __hfma2(relu2(t, z2), uh2(wr[q].z), acc2);
                    }
                    {
                        const __half2 t = __hadd2(__hadd2(uh2(av[q].w), uh2(bv[q].w)), uh2(cr[q].w));
                        acc2 = __hfma2(relu2(t, z2), uh2(wr[q].w), acc2);
                    }
                }
                accf[p] += __low2float(acc2) + __high2float(acc2);
            }
        }
        const float b2 = cfb2[0];
#pragma unroll
        for (int p = 0; p < 2; ++p) {
            const int j = j08 + p * 4 + jj2;
            const float z = accf[p] + b2;
            const float sg = 1.f / (1.f + expf(-z));
            const bool distinct = (i != j) && (j != k) && (i != k);
            conf[(i * NN + j) * NN + k] = distinct ? sg : 0.f;
        }
    }
}

extern "C" void kernel_launch(void* const* d_in, const int* in_sizes, int n_in,
                              void* d_out, int out_size, void* d_ws, size_t ws_size,
                              hipStream_t stream) {
    const float* x    = (const float*)d_in[0];
    const int*   node = (const int*)d_in[1];
    const float* ival = (const float*)d_in[2];
    const float* cdW1 = (const float*)d_in[3];
    const float* cdb1 = (const float*)d_in[4];
    const float* cdW2 = (const float*)d_in[5];
    const float* cdb2 = (const float*)d_in[6];
    const float* cdW3 = (const float*)d_in[7];
    const float* cdb3 = (const float*)d_in[8];
    const float* cfW1 = (const float*)d_in[9];
    const float* cfb1 = (const float*)d_in[10];
    const float* cfW2 = (const float*)d_in[11];
    const float* cfb2 = (const float*)d_in[12];
    const float* ipW1 = (const float*)d_in[13];
    const float* ipb1 = (const float*)d_in[14];
    const float* ipW2 = (const float*)d_in[15];
    const float* ipb2 = (const float*)d_in[16];

    float* out    = (float*)d_out;
    float* causal = out;                           // 4096
    float* conf   = out + NN * NN;                 // 262144
    float* out3   = out + NN * NN + NN * NN * NN;  // 8192
    float* wsf    = (float*)d_ws;

    k_stage<<<dim3(331), dim3(512), 0, stream>>>(
        x, node, ival, cdW1, cdb1, cdW2, cfW2, cfW1, cfb1,
        ipW1, ipb1, ipW2, ipb2, wsf, out3);
    k_main<<<dim3(768), dim3(256), 0, stream>>>(
        wsf, cdb2, cdW3, cdb3, cfb2, causal, conf);
}

// Round 17
// 24.728 us; speedup vs baseline: 4.6711x; 1.0353x over previous
//
#include <hip/hip_runtime.h>
#include <hip/hip_fp16.h>
#include <math.h>

#define NN 64
#define DD 128
#define HH 256

typedef __attribute__((ext_vector_type(8))) short short8;
typedef __attribute__((ext_vector_type(4))) float f32x4;

// ws layout (floats):
//   P    [64][256] @ 0        f32 (x @ cdW1[0:128] + cdb1)      — pairs
//   Q    [64][256] @ 16384    f32 (x @ cdW1[128:256])           — pairs
//   A16  [64][256] @ 32768    f16 rows (x @ cfW1[0:128] + cfb1) — triple
//   B16  [64][256] @ 40960    f16 rows (x @ cfW1[128:256])      — triple
//   C16q [32 g][64 k]uint4 @ 49152  f16, entry(g,k) = d 8g..8g+7 of node k
//   w16  [256] f16 @ 57344    (cfW2)
//   W2T  bf16 [128 c][256 t] @ 81920 (cdW2^T, bf16)             — pairs

__device__ __forceinline__ short f2bf(float f) {
    unsigned u = __float_as_uint(f);
    unsigned r = (u + 0x7fffu + ((u >> 16) & 1u)) >> 16;
    return (short)r;
}
__device__ __forceinline__ unsigned pack2(float lo, float hi) {
    __half2 h = __floats2half2_rn(lo, hi);
    return __builtin_bit_cast(unsigned, h);
}
__device__ __forceinline__ __half2 uh2(unsigned u) {
    return __builtin_bit_cast(__half2, u);
}
// packed ReLU: t * (t > 0)  (no __hmax2 in ROCm 7.2 headers)
__device__ __forceinline__ __half2 relu2(__half2 t, __half2 z2) {
    return __hmul2(t, __hgt2(t, z2));
}

// Kernel A, 512 thr, grid 331.
//   0..319 : projection p=bid>>6, node n=bid&63
//   320..327: cdW2 -> W2T bf16 transpose
//   328    : intervention MLP (512-thread version)
//   329,330: out3 row copies
__global__ __launch_bounds__(512) void k_stage(
    const float* __restrict__ x, const int* __restrict__ inode,
    const float* __restrict__ ival,
    const float* __restrict__ cdW1, const float* __restrict__ cdb1,
    const float* __restrict__ cdW2, const float* __restrict__ cfW2,
    const float* __restrict__ cfW1, const float* __restrict__ cfb1,
    const float* __restrict__ ipW1, const float* __restrict__ ipb1,
    const float* __restrict__ ipW2, const float* __restrict__ ipb2,
    float* __restrict__ ws, float* __restrict__ out3)
{
    __shared__ float xs[136];        // proj: x row; MLP: [x[node], v]
    __shared__ float4 red[8][64];    // proj/MLP-l1 reduce; MLP-l2 as [16][32]
    __shared__ float h_s[HH];        // MLP hidden
    const int bid = blockIdx.x;
    const int tid = threadIdx.x;
    if (bid < 320) {
        const int p = bid >> 6;
        const int n = bid & 63;
        if (tid < DD) xs[tid] = x[n * DD + tid];
        __syncthreads();
        const int c4 = tid & 63;   // output column group (4 cols)
        const int dg = tid >> 6;   // 0..7, 16 d's each
        const float* Wp = (p == 0) ? cdW1
                        : (p == 1) ? (cdW1 + DD * HH)
                                   : (cfW1 + (p - 2) * DD * HH);
        const float4* Wp4 = (const float4*)Wp;
        float4 w[16];
#pragma unroll
        for (int q = 0; q < 16; ++q) w[q] = Wp4[(dg * 16 + q) * 64 + c4];
        float4 acc = {0.f, 0.f, 0.f, 0.f};
#pragma unroll
        for (int q = 0; q < 16; ++q) {
            const float xv = xs[dg * 16 + q];
            acc.x += xv * w[q].x; acc.y += xv * w[q].y;
            acc.z += xv * w[q].z; acc.w += xv * w[q].w;
        }
        red[dg][c4] = acc;
        __syncthreads();
        if (tid < 64) {
            float4 s = {0.f, 0.f, 0.f, 0.f};
#pragma unroll
            for (int g = 0; g < 8; ++g) {
                const float4 r = red[g][tid];
                s.x += r.x; s.y += r.y; s.z += r.z; s.w += r.w;
            }
            if (p == 0) {
                const float4 b = ((const float4*)cdb1)[tid];
                s.x += b.x; s.y += b.y; s.z += b.z; s.w += b.w;
                ((float4*)(ws))[n * 64 + tid] = s;
            } else if (p == 1) {
                ((float4*)(ws + 16384))[n * 64 + tid] = s;
            } else if (p == 2) {
                const float4 b = ((const float4*)cfb1)[tid];
                s.x += b.x; s.y += b.y; s.z += b.z; s.w += b.w;
                ((uint2*)(ws + 32768))[n * 64 + tid] =
                    make_uint2(pack2(s.x, s.y), pack2(s.z, s.w));
            } else if (p == 3) {
                ((uint2*)(ws + 40960))[n * 64 + tid] =
                    make_uint2(pack2(s.x, s.y), pack2(s.z, s.w));
            } else {
                // C16q: thread t holds d = 4t..4t+3 of node n
                ((uint2*)(ws + 49152))[(((tid >> 1) * 64 + n) << 1) + (tid & 1)] =
                    make_uint2(pack2(s.x, s.y), pack2(s.z, s.w));
            }
        }
        // w16 staging piggybacked on block p==4,n==0 (threads 128..191)
        if (bid == 256 && tid >= 128 && tid < 192) {
            const int u = tid - 128;
            const float4 w4 = ((const float4*)cfW2)[u];
            ((uint2*)(ws + 57344))[u] =
                make_uint2(pack2(w4.x, w4.y), pack2(w4.z, w4.w));
        }
    } else if (bid < 328) {
        // W2T[c][t] = bf16(cdW2[t][c]); 16 c's per block, 32 threads per c
        unsigned short* W2T = (unsigned short*)(ws + 81920);
        const int c  = (bid - 320) * 16 + (tid >> 5);
        const int t0 = (tid & 31) * 8;
        float v[8];
#pragma unroll
        for (int e = 0; e < 8; ++e) v[e] = cdW2[(t0 + e) * 128 + c];
        unsigned short pk[8];
#pragma unroll
        for (int e = 0; e < 8; ++e) pk[e] = (unsigned short)f2bf(v[e]);
        *(ulong2*)(W2T + c * HH + t0) = *(ulong2*)pk;
    } else if (bid == 328) {
        // ---- intervention MLP, 512 threads
        const int node = inode[0];
        if (tid < DD) xs[tid] = x[node * DD + tid];
        if (tid == DD) xs[DD] = ival[0];
        __syncthreads();
        {   // layer 1: 256 cols, K=129; dg covers 16 d's
            const int c4 = tid & 63;
            const int dg = tid >> 6;   // 0..7
            const float4* W1v = (const float4*)ipW1;
            float4 acc = {0.f, 0.f, 0.f, 0.f};
#pragma unroll
            for (int r = 0; r < 16; ++r) {
                const int d = dg * 16 + r;
                const float xv = xs[d];
                const float4 w = W1v[d * 64 + c4];
                acc.x += xv * w.x; acc.y += xv * w.y;
                acc.z += xv * w.z; acc.w += xv * w.w;
            }
            if (dg == 0) {
                const float xv = xs[128];
                const float4 w = W1v[128 * 64 + c4];
                acc.x += xv * w.x; acc.y += xv * w.y;
                acc.z += xv * w.z; acc.w += xv * w.w;
            }
            red[dg][c4] = acc;
        }
        __syncthreads();
        if (tid < 64) {
            float4 s = ((const float4*)ipb1)[tid];
#pragma unroll
            for (int g = 0; g < 8; ++g) {
                const float4 r = red[g][tid];
                s.x += r.x; s.y += r.y; s.z += r.z; s.w += r.w;
            }
            float4 h;
            h.x = fmaxf(s.x, 0.f); h.y = fmaxf(s.y, 0.f);
            h.z = fmaxf(s.z, 0.f); h.w = fmaxf(s.w, 0.f);
            ((float4*)h_s)[tid] = h;
        }
        __syncthreads();
        {   // layer 2: 128 cols, K=256; ug covers 16 u's
            const int c4 = tid & 31;
            const int ug = tid >> 5;   // 0..15
            const float4* W2v = (const float4*)ipW2;
            float4 acc = {0.f, 0.f, 0.f, 0.f};
#pragma unroll
            for (int r = 0; r < 16; ++r) {
                const int uu = ug * 16 + r;
                const float hv = h_s[uu];
                const float4 w = W2v[uu * 32 + c4];
                acc.x += hv * w.x; acc.y += hv * w.y;
                acc.z += hv * w.z; acc.w += hv * w.w;
            }
            ((float4*)red)[ug * 32 + c4] = acc;
        }
        __syncthreads();
        if (tid < 32) {
            float4 s = ((const float4*)ipb2)[tid];
#pragma unroll
            for (int g = 0; g < 16; ++g) {
                const float4 r = ((const float4*)red)[g * 32 + tid];
                s.x += r.x; s.y += r.y; s.z += r.z; s.w += r.w;
            }
            ((float4*)(out3 + node * DD))[tid] = s;
        }
    } else {
        // ---- out3 copies (rows != node), 32 rows per block, 16 thr/row
        const int node = inode[0];
        const int n = (bid - 329) * 32 + (tid >> 4);
        const int part = tid & 15;
        if (n != node) {
            const float4* src = (const float4*)(x + n * DD);
            float4* dst = (float4*)(out3 + n * DD);
            dst[part * 2]     = src[part * 2];
            dst[part * 2 + 1] = src[part * 2 + 1];
        }
    }
}

// Kernel B, 256 thr, grid 1280.
//   bid <  256: pairs MFMA unit (i=bid>>2, j0=(bid&3)*16)
//   bid >= 256: triple unit, 1024 blocks x 4 j's (one j per thread-quarter)
__global__ __launch_bounds__(256) void k_main(
    const float* __restrict__ ws,
    const float* __restrict__ cdb2, const float* __restrict__ cdW3,
    const float* __restrict__ cdb3, const float* __restrict__ cfb2,
    float* __restrict__ causal, float* __restrict__ conf)
{
    const int bid = blockIdx.x;
    const int tid = threadIdx.x;
    if (bid < 256) {
        // ---- causal pairs via bf16 MFMA, no LDS main loop
        const int i  = bid >> 2;
        const int j0 = (bid & 3) * 16;
        const int wid  = tid >> 6;
        const int lane = tid & 63;
        const int lo = lane & 15;
        const int hi = lane >> 4;
        const int n0 = wid * 32;

        const float* Prow = ws + i * HH;
        const float* Qrow = ws + 16384 + (j0 + lo) * HH;
        const unsigned short* W2T = (const unsigned short*)(ws + 81920);

        f32x4 acc0 = {0.f, 0.f, 0.f, 0.f};
        f32x4 acc1 = {0.f, 0.f, 0.f, 0.f};
#pragma unroll
        for (int step = 0; step < 8; ++step) {
            const int kb = step * 32 + hi * 8;
            const float4 pa = *(const float4*)(Prow + kb);
            const float4 pb = *(const float4*)(Prow + kb + 4);
            const float4 qa = *(const float4*)(Qrow + kb);
            const float4 qb = *(const float4*)(Qrow + kb + 4);
            short8 af;
            af[0] = f2bf(fmaxf(pa.x + qa.x, 0.f));
            af[1] = f2bf(fmaxf(pa.y + qa.y, 0.f));
            af[2] = f2bf(fmaxf(pa.z + qa.z, 0.f));
            af[3] = f2bf(fmaxf(pa.w + qa.w, 0.f));
            af[4] = f2bf(fmaxf(pb.x + qb.x, 0.f));
            af[5] = f2bf(fmaxf(pb.y + qb.y, 0.f));
            af[6] = f2bf(fmaxf(pb.z + qb.z, 0.f));
            af[7] = f2bf(fmaxf(pb.w + qb.w, 0.f));
            const short8 b0 = *(const short8*)(W2T + (n0 + lo) * HH + kb);
            const short8 b1 = *(const short8*)(W2T + (n0 + 16 + lo) * HH + kb);
            acc0 = __builtin_amdgcn_mfma_f32_16x16x32_bf16(af, b0, acc0, 0, 0, 0);
            acc1 = __builtin_amdgcn_mfma_f32_16x16x32_bf16(af, b1, acc1, 0, 0, 0);
        }
        const int c0 = n0 + lo;
        const int c1 = n0 + 16 + lo;
        const float b2a = cdb2[c0], b2b = cdb2[c1];
        const float w3a = cdW3[c0], w3b = cdW3[c1];
        float pr[4];
#pragma unroll
        for (int r = 0; r < 4; ++r) {
            pr[r] = fmaxf(acc0[r] + b2a, 0.f) * w3a
                  + fmaxf(acc1[r] + b2b, 0.f) * w3b;
        }
#pragma unroll
        for (int m = 1; m <= 8; m <<= 1) {
#pragma unroll
            for (int r = 0; r < 4; ++r) pr[r] += __shfl_xor(pr[r], m, 64);
        }
        __shared__ float zp[4][16];
        if (lo == 0) {
#pragma unroll
            for (int r = 0; r < 4; ++r) zp[wid][hi * 4 + r] = pr[r];
        }
        __syncthreads();
        if (tid < 16) {
            const float z = zp[0][tid] + zp[1][tid] + zp[2][tid] + zp[3][tid] + cdb3[0];
            const float sg = 1.f / (1.f + expf(-z));
            const int j = j0 + tid;
            causal[i * NN + j] = (i == j) ? 0.f : sg;
        }
    } else {
        // ---- confounder triples, packed-f16, zero-LDS, 4 j's per block
        // (one j per thread; 1024 blocks -> ~5 blocks/CU with pairs)
        const int u = bid - 256;
        const int i   = u >> 4;
        const int j   = (u & 15) * 4 + (tid >> 6);
        const int k   = tid & 63;
        const uint4* C16v = (const uint4*)(ws + 49152);          // [g*64 + k]
        const uint4* A16v = (const uint4*)(ws + 32768) + i * 32; // row i
        const uint4* B16v = (const uint4*)(ws + 40960) + j * 32; // row j
        const uint4* W16v = (const uint4*)(ws + 57344);          // 32 entries
        const __half2 z2 = __float2half2_rn(0.f);
        float accf = 0.f;
        for (int ch = 0; ch < 8; ++ch) {   // 4 g-groups per chunk, 32 total
            uint4 cr[4], av[4], wr[4], bv[4];
#pragma unroll
            for (int q = 0; q < 4; ++q) {
                const int g = ch * 4 + q;
                cr[q] = C16v[g * 64 + k];   // coalesced over k-lanes
                av[q] = A16v[g];            // wave-uniform
                bv[q] = B16v[g];            // wave-uniform (per 64-lane wave)
                wr[q] = W16v[g];            // wave-uniform
            }
            __half2 acc2 = z2;
#pragma unroll
            for (int q = 0; q < 4; ++q) {
                {
                    const __half2 t = __hadd2(__hadd2(uh2(av[q].x), uh2(bv[q].x)), uh2(cr[q].x));
                    acc2 = __hfma2(relu2(t, z2), uh2(wr[q].x), acc2);
                }
                {
                    const __half2 t = __hadd2(__hadd2(uh2(av[q].y), uh2(bv[q].y)), uh2(cr[q].y));
                    acc2 = __hfma2(relu2(t, z2), uh2(wr[q].y), acc2);
                }
                {
                    const __half2 t = __hadd2(__hadd2(uh2(av[q].z), uh2(bv[q].z)), uh2(cr[q].z));
                    acc2 = __hfma2(relu2(t, z2), uh2(wr[q].z), acc2);
                }
                {
                    const __half2 t = __hadd2(__hadd2(uh2(av[q].w), uh2(bv[q].w)), uh2(cr[q].w));
                    acc2 = __hfma2(relu2(t, z2), uh2(wr[q].w), acc2);
                }
            }
            accf += __low2float(acc2) + __high2float(acc2);
        }
        const float z = accf + cfb2[0];
        const float sg = 1.f / (1.f + expf(-z));
        const bool distinct = (i != j) && (j != k) && (i != k);
        conf[(i * NN + j) * NN + k] = distinct ? sg : 0.f;
    }
}

extern "C" void kernel_launch(void* const* d_in, const int* in_sizes, int n_in,
                              void* d_out, int out_size, void* d_ws, size_t ws_size,
                              hipStream_t stream) {
    const float* x    = (const float*)d_in[0];
    const int*   node = (const int*)d_in[1];
    const float* ival = (const float*)d_in[2];
    const float* cdW1 = (const float*)d_in[3];
    const float* cdb1 = (const float*)d_in[4];
    const float* cdW2 = (const float*)d_in[5];
    const float* cdb2 = (const float*)d_in[6];
    const float* cdW3 = (const float*)d_in[7];
    const float* cdb3 = (const float*)d_in[8];
    const float* cfW1 = (const float*)d_in[9];
    const float* cfb1 = (const float*)d_in[10];
    const float* cfW2 = (const float*)d_in[11];
    const float* cfb2 = (const float*)d_in[12];
    const float* ipW1 = (const float*)d_in[13];
    const float* ipb1 = (const float*)d_in[14];
    const float* ipW2 = (const float*)d_in[15];
    const float* ipb2 = (const float*)d_in[16];

    float* out    = (float*)d_out;
    float* causal = out;                           // 4096
    float* conf   = out + NN * NN;                 // 262144
    float* out3   = out + NN * NN + NN * NN * NN;  // 8192
    float* wsf    = (float*)d_ws;

    k_stage<<<dim3(331), dim3(512), 0, stream>>>(
        x, node, ival, cdW1, cdb1, cdW2, cfW2, cfW1, cfb1,
        ipW1, ipb1, ipW2, ipb2, wsf, out3);
    k_main<<<dim3(1280), dim3(256), 0, stream>>>(
        wsf, cdb2, cdW3, cdb3, cfb2, causal, conf);
}

// Round 18
// 22.969 us; speedup vs baseline: 5.0288x; 1.0766x over previous
//
#include <hip/hip_runtime.h>
#include <hip/hip_fp16.h>
#include <math.h>

#define NN 64
#define DD 128
#define HH 256

typedef __attribute__((ext_vector_type(8))) short short8;
typedef __attribute__((ext_vector_type(4))) float f32x4;

// ws layout (floats):
//   P    [64][256] @ 0        f32 (x @ cdW1[0:128] + cdb1)      — pairs
//   Q    [64][256] @ 16384    f32 (x @ cdW1[128:256])           — pairs
//   A16  [64][256] @ 32768    f16 rows (x @ cfW1[0:128] + cfb1) — triple
//   B16  [64][256] @ 40960    f16 rows (x @ cfW1[128:256])      — triple
//   C16q [32 g][64 k]uint4 @ 49152  f16, entry(g,k) = d 8g..8g+7 of node k
//   w16  [256] f16 @ 57344    (cfW2)
//   W2T  bf16 [128 c][256 t] @ 81920 (cdW2^T, bf16)             — pairs

__device__ __forceinline__ short f2bf(float f) {
    unsigned u = __float_as_uint(f);
    unsigned r = (u + 0x7fffu + ((u >> 16) & 1u)) >> 16;
    return (short)r;
}
__device__ __forceinline__ unsigned pack2(float lo, float hi) {
    __half2 h = __floats2half2_rn(lo, hi);
    return __builtin_bit_cast(unsigned, h);
}
__device__ __forceinline__ __half2 uh2(unsigned u) {
    return __builtin_bit_cast(__half2, u);
}
// packed ReLU: t * (t > 0)  (no __hmax2 in ROCm 7.2 headers)
__device__ __forceinline__ __half2 relu2(__half2 t, __half2 z2) {
    return __hmul2(t, __hgt2(t, z2));
}

// Kernel A, 512 thr, grid 331.
//   0..319 : projection p=bid>>6, node n=bid&63
//   320..327: cdW2 -> W2T bf16 transpose
//   328    : intervention MLP (512-thread version)
//   329,330: out3 row copies
__global__ __launch_bounds__(512) void k_stage(
    const float* __restrict__ x, const int* __restrict__ inode,
    const float* __restrict__ ival,
    const float* __restrict__ cdW1, const float* __restrict__ cdb1,
    const float* __restrict__ cdW2, const float* __restrict__ cfW2,
    const float* __restrict__ cfW1, const float* __restrict__ cfb1,
    const float* __restrict__ ipW1, const float* __restrict__ ipb1,
    const float* __restrict__ ipW2, const float* __restrict__ ipb2,
    float* __restrict__ ws, float* __restrict__ out3)
{
    __shared__ float xs[136];        // proj: x row; MLP: [x[node], v]
    __shared__ float4 red[8][64];    // proj/MLP-l1 reduce; MLP-l2 as [16][32]
    __shared__ float h_s[HH];        // MLP hidden
    const int bid = blockIdx.x;
    const int tid = threadIdx.x;
    if (bid < 320) {
        const int p = bid >> 6;
        const int n = bid & 63;
        if (tid < DD) xs[tid] = x[n * DD + tid];
        __syncthreads();
        const int c4 = tid & 63;   // output column group (4 cols)
        const int dg = tid >> 6;   // 0..7, 16 d's each
        const float* Wp = (p == 0) ? cdW1
                        : (p == 1) ? (cdW1 + DD * HH)
                                   : (cfW1 + (p - 2) * DD * HH);
        const float4* Wp4 = (const float4*)Wp;
        float4 w[16];
#pragma unroll
        for (int q = 0; q < 16; ++q) w[q] = Wp4[(dg * 16 + q) * 64 + c4];
        float4 acc = {0.f, 0.f, 0.f, 0.f};
#pragma unroll
        for (int q = 0; q < 16; ++q) {
            const float xv = xs[dg * 16 + q];
            acc.x += xv * w[q].x; acc.y += xv * w[q].y;
            acc.z += xv * w[q].z; acc.w += xv * w[q].w;
        }
        red[dg][c4] = acc;
        __syncthreads();
        if (tid < 64) {
            float4 s = {0.f, 0.f, 0.f, 0.f};
#pragma unroll
            for (int g = 0; g < 8; ++g) {
                const float4 r = red[g][tid];
                s.x += r.x; s.y += r.y; s.z += r.z; s.w += r.w;
            }
            if (p == 0) {
                const float4 b = ((const float4*)cdb1)[tid];
                s.x += b.x; s.y += b.y; s.z += b.z; s.w += b.w;
                ((float4*)(ws))[n * 64 + tid] = s;
            } else if (p == 1) {
                ((float4*)(ws + 16384))[n * 64 + tid] = s;
            } else if (p == 2) {
                const float4 b = ((const float4*)cfb1)[tid];
                s.x += b.x; s.y += b.y; s.z += b.z; s.w += b.w;
                ((uint2*)(ws + 32768))[n * 64 + tid] =
                    make_uint2(pack2(s.x, s.y), pack2(s.z, s.w));
            } else if (p == 3) {
                ((uint2*)(ws + 40960))[n * 64 + tid] =
                    make_uint2(pack2(s.x, s.y), pack2(s.z, s.w));
            } else {
                // C16q: thread t holds d = 4t..4t+3 of node n
                ((uint2*)(ws + 49152))[(((tid >> 1) * 64 + n) << 1) + (tid & 1)] =
                    make_uint2(pack2(s.x, s.y), pack2(s.z, s.w));
            }
        }
        // w16 staging piggybacked on block p==4,n==0 (threads 128..191)
        if (bid == 256 && tid >= 128 && tid < 192) {
            const int u = tid - 128;
            const float4 w4 = ((const float4*)cfW2)[u];
            ((uint2*)(ws + 57344))[u] =
                make_uint2(pack2(w4.x, w4.y), pack2(w4.z, w4.w));
        }
    } else if (bid < 328) {
        // W2T[c][t] = bf16(cdW2[t][c]); 16 c's per block, 32 threads per c
        unsigned short* W2T = (unsigned short*)(ws + 81920);
        const int c  = (bid - 320) * 16 + (tid >> 5);
        const int t0 = (tid & 31) * 8;
        float v[8];
#pragma unroll
        for (int e = 0; e < 8; ++e) v[e] = cdW2[(t0 + e) * 128 + c];
        unsigned short pk[8];
#pragma unroll
        for (int e = 0; e < 8; ++e) pk[e] = (unsigned short)f2bf(v[e]);
        *(ulong2*)(W2T + c * HH + t0) = *(ulong2*)pk;
    } else if (bid == 328) {
        // ---- intervention MLP, 512 threads
        const int node = inode[0];
        if (tid < DD) xs[tid] = x[node * DD + tid];
        if (tid == DD) xs[DD] = ival[0];
        __syncthreads();
        {   // layer 1: 256 cols, K=129; dg covers 16 d's
            const int c4 = tid & 63;
            const int dg = tid >> 6;   // 0..7
            const float4* W1v = (const float4*)ipW1;
            float4 acc = {0.f, 0.f, 0.f, 0.f};
#pragma unroll
            for (int r = 0; r < 16; ++r) {
                const int d = dg * 16 + r;
                const float xv = xs[d];
                const float4 w = W1v[d * 64 + c4];
                acc.x += xv * w.x; acc.y += xv * w.y;
                acc.z += xv * w.z; acc.w += xv * w.w;
            }
            if (dg == 0) {
                const float xv = xs[128];
                const float4 w = W1v[128 * 64 + c4];
                acc.x += xv * w.x; acc.y += xv * w.y;
                acc.z += xv * w.z; acc.w += xv * w.w;
            }
            red[dg][c4] = acc;
        }
        __syncthreads();
        if (tid < 64) {
            float4 s = ((const float4*)ipb1)[tid];
#pragma unroll
            for (int g = 0; g < 8; ++g) {
                const float4 r = red[g][tid];
                s.x += r.x; s.y += r.y; s.z += r.z; s.w += r.w;
            }
            float4 h;
            h.x = fmaxf(s.x, 0.f); h.y = fmaxf(s.y, 0.f);
            h.z = fmaxf(s.z, 0.f); h.w = fmaxf(s.w, 0.f);
            ((float4*)h_s)[tid] = h;
        }
        __syncthreads();
        {   // layer 2: 128 cols, K=256; ug covers 16 u's
            const int c4 = tid & 31;
            const int ug = tid >> 5;   // 0..15
            const float4* W2v = (const float4*)ipW2;
            float4 acc = {0.f, 0.f, 0.f, 0.f};
#pragma unroll
            for (int r = 0; r < 16; ++r) {
                const int uu = ug * 16 + r;
                const float hv = h_s[uu];
                const float4 w = W2v[uu * 32 + c4];
                acc.x += hv * w.x; acc.y += hv * w.y;
                acc.z += hv * w.z; acc.w += hv * w.w;
            }
            ((float4*)red)[ug * 32 + c4] = acc;
        }
        __syncthreads();
        if (tid < 32) {
            float4 s = ((const float4*)ipb2)[tid];
#pragma unroll
            for (int g = 0; g < 16; ++g) {
                const float4 r = ((const float4*)red)[g * 32 + tid];
                s.x += r.x; s.y += r.y; s.z += r.z; s.w += r.w;
            }
            ((float4*)(out3 + node * DD))[tid] = s;
        }
    } else {
        // ---- out3 copies (rows != node), 32 rows per block, 16 thr/row
        const int node = inode[0];
        const int n = (bid - 329) * 32 + (tid >> 4);
        const int part = tid & 15;
        if (n != node) {
            const float4* src = (const float4*)(x + n * DD);
            float4* dst = (float4*)(out3 + n * DD);
            dst[part * 2]     = src[part * 2];
            dst[part * 2 + 1] = src[part * 2 + 1];
        }
    }
}

// Kernel B, 256 thr, grid 1280.
//   bid <  256: pairs MFMA unit (i=bid>>2, j0=(bid&3)*16)
//   bid >= 256: triple unit, 1024 blocks x 4 j's (one j per wave;
//               j forced to SGPR via readfirstlane -> B loads on scalar pipe)
__global__ __launch_bounds__(256) void k_main(
    const float* __restrict__ ws,
    const float* __restrict__ cdb2, const float* __restrict__ cdW3,
    const float* __restrict__ cdb3, const float* __restrict__ cfb2,
    float* __restrict__ causal, float* __restrict__ conf)
{
    const int bid = blockIdx.x;
    const int tid = threadIdx.x;
    if (bid < 256) {
        // ---- causal pairs via bf16 MFMA, no LDS main loop
        const int i  = bid >> 2;
        const int j0 = (bid & 3) * 16;
        const int wid  = tid >> 6;
        const int lane = tid & 63;
        const int lo = lane & 15;
        const int hi = lane >> 4;
        const int n0 = wid * 32;

        const float* Prow = ws + i * HH;
        const float* Qrow = ws + 16384 + (j0 + lo) * HH;
        const unsigned short* W2T = (const unsigned short*)(ws + 81920);

        f32x4 acc0 = {0.f, 0.f, 0.f, 0.f};
        f32x4 acc1 = {0.f, 0.f, 0.f, 0.f};
#pragma unroll
        for (int step = 0; step < 8; ++step) {
            const int kb = step * 32 + hi * 8;
            const float4 pa = *(const float4*)(Prow + kb);
            const float4 pb = *(const float4*)(Prow + kb + 4);
            const float4 qa = *(const float4*)(Qrow + kb);
            const float4 qb = *(const float4*)(Qrow + kb + 4);
            short8 af;
            af[0] = f2bf(fmaxf(pa.x + qa.x, 0.f));
            af[1] = f2bf(fmaxf(pa.y + qa.y, 0.f));
            af[2] = f2bf(fmaxf(pa.z + qa.z, 0.f));
            af[3] = f2bf(fmaxf(pa.w + qa.w, 0.f));
            af[4] = f2bf(fmaxf(pb.x + qb.x, 0.f));
            af[5] = f2bf(fmaxf(pb.y + qb.y, 0.f));
            af[6] = f2bf(fmaxf(pb.z + qb.z, 0.f));
            af[7] = f2bf(fmaxf(pb.w + qb.w, 0.f));
            const short8 b0 = *(const short8*)(W2T + (n0 + lo) * HH + kb);
            const short8 b1 = *(const short8*)(W2T + (n0 + 16 + lo) * HH + kb);
            acc0 = __builtin_amdgcn_mfma_f32_16x16x32_bf16(af, b0, acc0, 0, 0, 0);
            acc1 = __builtin_amdgcn_mfma_f32_16x16x32_bf16(af, b1, acc1, 0, 0, 0);
        }
        const int c0 = n0 + lo;
        const int c1 = n0 + 16 + lo;
        const float b2a = cdb2[c0], b2b = cdb2[c1];
        const float w3a = cdW3[c0], w3b = cdW3[c1];
        float pr[4];
#pragma unroll
        for (int r = 0; r < 4; ++r) {
            pr[r] = fmaxf(acc0[r] + b2a, 0.f) * w3a
                  + fmaxf(acc1[r] + b2b, 0.f) * w3b;
        }
#pragma unroll
        for (int m = 1; m <= 8; m <<= 1) {
#pragma unroll
            for (int r = 0; r < 4; ++r) pr[r] += __shfl_xor(pr[r], m, 64);
        }
        __shared__ float zp[4][16];
        if (lo == 0) {
#pragma unroll
            for (int r = 0; r < 4; ++r) zp[wid][hi * 4 + r] = pr[r];
        }
        __syncthreads();
        if (tid < 16) {
            const float z = zp[0][tid] + zp[1][tid] + zp[2][tid] + zp[3][tid] + cdb3[0];
            const float sg = 1.f / (1.f + expf(-z));
            const int j = j0 + tid;
            causal[i * NN + j] = (i == j) ? 0.f : sg;
        }
    } else {
        // ---- confounder triples, packed-f16, zero-LDS, 4 j's per block
        const int u = bid - 256;
        const int i = u >> 4;
        // j is wave-uniform (tid>>6 = wave index); readfirstlane proves it
        // to the compiler -> B16v base lives in SGPRs -> s_load (scalar pipe)
        const int j = __builtin_amdgcn_readfirstlane((u & 15) * 4 + (tid >> 6));
        const int k = tid & 63;
        const uint4* C16v = (const uint4*)(ws + 49152);          // [g*64 + k]
        const uint4* A16v = (const uint4*)(ws + 32768) + i * 32; // row i (scalar)
        const uint4* B16v = (const uint4*)(ws + 40960) + j * 32; // row j (scalar)
        const uint4* W16v = (const uint4*)(ws + 57344);          // 32 (scalar)
        const __half2 z2 = __float2half2_rn(0.f);
        float accf = 0.f;
        for (int ch = 0; ch < 8; ++ch) {   // 4 g-groups per chunk, 32 total
            uint4 cr[4], av[4], wr[4], bv[4];
#pragma unroll
            for (int q = 0; q < 4; ++q) {
                const int g = ch * 4 + q;
                cr[q] = C16v[g * 64 + k];   // coalesced over k-lanes (vector)
                av[q] = A16v[g];            // scalar path
                bv[q] = B16v[g];            // scalar path (readfirstlane'd j)
                wr[q] = W16v[g];            // scalar path
            }
            __half2 acc2 = z2;
#pragma unroll
            for (int q = 0; q < 4; ++q) {
                {
                    const __half2 t = __hadd2(__hadd2(uh2(av[q].x), uh2(bv[q].x)), uh2(cr[q].x));
                    acc2 = __hfma2(relu2(t, z2), uh2(wr[q].x), acc2);
                }
                {
                    const __half2 t = __hadd2(__hadd2(uh2(av[q].y), uh2(bv[q].y)), uh2(cr[q].y));
                    acc2 = __hfma2(relu2(t, z2), uh2(wr[q].y), acc2);
                }
                {
                    const __half2 t = __hadd2(__hadd2(uh2(av[q].z), uh2(bv[q].z)), uh2(cr[q].z));
                    acc2 = __hfma2(relu2(t, z2), uh2(wr[q].z), acc2);
                }
                {
                    const __half2 t = __hadd2(__hadd2(uh2(av[q].w), uh2(bv[q].w)), uh2(cr[q].w));
                    acc2 = __hfma2(relu2(t, z2), uh2(wr[q].w), acc2);
                }
            }
            accf += __low2float(acc2) + __high2float(acc2);
        }
        const float z = accf + cfb2[0];
        const float sg = 1.f / (1.f + expf(-z));
        const bool distinct = (i != j) && (j != k) && (i != k);
        conf[(i * NN + j) * NN + k] = distinct ? sg : 0.f;
    }
}

extern "C" void kernel_launch(void* const* d_in, const int* in_sizes, int n_in,
                              void* d_out, int out_size, void* d_ws, size_t ws_size,
                              hipStream_t stream) {
    const float* x    = (const float*)d_in[0];
    const int*   node = (const int*)d_in[1];
    const float* ival = (const float*)d_in[2];
    const float* cdW1 = (const float*)d_in[3];
    const float* cdb1 = (const float*)d_in[4];
    const float* cdW2 = (const float*)d_in[5];
    const float* cdb2 = (const float*)d_in[6];
    const float* cdW3 = (const float*)d_in[7];
    const float* cdb3 = (const float*)d_in[8];
    const float* cfW1 = (const float*)d_in[9];
    const float* cfb1 = (const float*)d_in[10];
    const float* cfW2 = (const float*)d_in[11];
    const float* cfb2 = (const float*)d_in[12];
    const float* ipW1 = (const float*)d_in[13];
    const float* ipb1 = (const float*)d_in[14];
    const float* ipW2 = (const float*)d_in[15];
    const float* ipb2 = (const float*)d_in[16];

    float* out    = (float*)d_out;
    float* causal = out;                           // 4096
    float* conf   = out + NN * NN;                 // 262144
    float* out3   = out + NN * NN + NN * NN * NN;  // 8192
    float* wsf    = (float*)d_ws;

    k_stage<<<dim3(331), dim3(512), 0, stream>>>(
        x, node, ival, cdW1, cdb1, cdW2, cfW2, cfW1, cfb1,
        ipW1, ipb1, ipW2, ipb2, wsf, out3);
    k_main<<<dim3(1280), dim3(256), 0, stream>>>(
        wsf, cdb2, cdW3, cdb3, cfb2, causal, conf);
}